// Round 1
// baseline (982.270 us; speedup 1.0000x reference)
//
#include <hip/hip_runtime.h>
#include <hip/hip_bf16.h>

// Problem constants (B=8, C=256, H=W=64, OG=4, Cg=64, K=9, C_off=72)
#define BATCH 8
#define CIN   256
#define HH    64
#define WW    64
#define OG    4
#define CG    64
#define COFF  72
#define CK    8   // input-channel chunk for conv1

// ---------------------------------------------------------------------------
// Kernel 1: offsets = conv3x3(x, w_off) + b_off
// grid = B*H blocks, 256 threads. Each block computes all 72 oc for one (b,h)
// row. Thread t: w = t&63, q = t>>6 owns oc = q*18 + j (j<18).
// ---------------------------------------------------------------------------
__global__ __launch_bounds__(256) void conv_off_kernel(
    const float* __restrict__ x, const float* __restrict__ w_off,
    const float* __restrict__ b_off, float* __restrict__ offs)
{
    const int b = blockIdx.x >> 6;
    const int h = blockIdx.x & 63;
    const int t = threadIdx.x;
    const int w = t & 63;
    const int q = t >> 6;

    __shared__ float xs[3][CK][WW + 2];   // zero-padded input rows
    __shared__ float wt[9][CK][COFF];     // [tap][cc][oc]

    float acc[18];
#pragma unroll
    for (int j = 0; j < 18; ++j) acc[j] = 0.f;

    for (int c0 = 0; c0 < CIN; c0 += CK) {
        __syncthreads();
        // stage x rows (zero-padded in h and w)
        for (int i = t; i < 3 * CK * (WW + 2); i += 256) {
            int wp  = i % (WW + 2);
            int rem = i / (WW + 2);
            int cc  = rem % CK;
            int ky  = rem / CK;
            int yy  = h + ky - 1;
            int xx  = wp - 1;
            float v = 0.f;
            if (yy >= 0 && yy < HH && xx >= 0 && xx < WW)
                v = x[(((size_t)b * CIN + c0 + cc) * HH + yy) * WW + xx];
            xs[ky][cc][wp] = v;
        }
        // stage weights, transposed so oc is contiguous
        for (int i = t; i < 9 * CK * COFF; i += 256) {
            int oc  = i % COFF;
            int rem = i / COFF;
            int cc  = rem % CK;
            int tap = rem / CK;
            wt[tap][cc][oc] = w_off[((size_t)oc * CIN + c0 + cc) * 9 + tap];
        }
        __syncthreads();

        for (int tap = 0; tap < 9; ++tap) {
            const int ky = tap / 3, kx = tap % 3;
#pragma unroll
            for (int cc = 0; cc < CK; ++cc) {
                float xv = xs[ky][cc][w + kx];
#pragma unroll
                for (int j = 0; j < 18; ++j)
                    acc[j] += xv * wt[tap][cc][q * 18 + j];
            }
        }
    }
#pragma unroll
    for (int j = 0; j < 18; ++j) {
        int oc = q * 18 + j;
        offs[(((size_t)b * COFF + oc) * HH + h) * WW + w] = acc[j] + b_off[oc];
    }
}

// ---------------------------------------------------------------------------
// Kernel 2: deformable conv. grid = B*OG*H blocks, 256 threads.
// Block handles one (b, g, h) row: all 64 out-channels x 64 w.
// Per tap k: wave0 computes bilinear params per w; all threads gather the
// 64(ch) x 64(w) sampled tile into LDS; stage 64x64 weight slice; FMA sweep.
// Thread t: w = t&63, q = t>>6 owns o = q*16 + j (j<16).
// ---------------------------------------------------------------------------
__global__ __launch_bounds__(256) void deform_kernel(
    const float* __restrict__ x, const float* __restrict__ offs,
    const float* __restrict__ w_def, const float* __restrict__ b_def,
    float* __restrict__ out)
{
    const int h  = blockIdx.x & 63;
    const int bg = blockIdx.x >> 6;
    const int g  = bg & 3;
    const int b  = bg >> 2;
    const int t  = threadIdx.x;
    const int w  = t & 63;
    const int q  = t >> 6;

    __shared__ float vlds[CG][WW];    // sampled values [c][w]
    __shared__ float wt2[CG][CG];     // weights [c][o] for current tap
    __shared__ int   sidx[4][WW];     // clamped linear index per corner per w
    __shared__ float swgt[4][WW];     // bilinear weight * validity

    float acc[16];
#pragma unroll
    for (int j = 0; j < 16; ++j) acc[j] = 0.f;

    const float* xg = x + ((size_t)(b * CIN + g * CG)) * (HH * WW);

    for (int k = 0; k < 9; ++k) {
        __syncthreads();
        if (t < 64) {
            const int ky = k / 3 - 1, kx = k % 3 - 1;
            // offsets channel = g*18 + k*2 + {0,1}; layout [B,72,H,W]
            size_t obase = (((size_t)b * COFF + g * 18 + k * 2) * HH + h) * WW + w;
            float dy = offs[obase];
            float dx = offs[obase + (size_t)HH * WW];
            float py = dy + (float)(h + ky);
            float px = dx + (float)(w + kx);
            float y0 = floorf(py), x0 = floorf(px);
            float fy = py - y0, fx = px - x0;
#pragma unroll
            for (int cn = 0; cn < 4; ++cn) {
                float yy = y0 + (float)(cn >> 1);
                float xx = x0 + (float)(cn & 1);
                float wy = (cn >> 1) ? fy : (1.f - fy);
                float wx = (cn & 1) ? fx : (1.f - fx);
                bool valid = (yy >= 0.f) && (yy < (float)HH) &&
                             (xx >= 0.f) && (xx < (float)WW);
                int yi = (int)fminf(fmaxf(yy, 0.f), (float)(HH - 1));
                int xi = (int)fminf(fmaxf(xx, 0.f), (float)(WW - 1));
                sidx[cn][w] = yi * WW + xi;
                swgt[cn][w] = valid ? (wy * wx) : 0.f;
            }
        }
        // stage weight slice for this (g, k): wt2[c][o] = w_def[g*64+o][c][k]
        for (int i = t; i < CG * CG; i += 256) {
            int o = i >> 6, c = i & 63;
            wt2[c][o] = w_def[((size_t)(g * CG + o) * CG + c) * 9 + k];
        }
        __syncthreads();

        // gather: thread (q,w) samples channels c = q*16+j at pixel w
        int   i0 = sidx[0][w], i1 = sidx[1][w], i2 = sidx[2][w], i3 = sidx[3][w];
        float g0 = swgt[0][w], g1 = swgt[1][w], g2 = swgt[2][w], g3 = swgt[3][w];
#pragma unroll
        for (int j = 0; j < 16; ++j) {
            int c = q * 16 + j;
            const float* xc = xg + (size_t)c * (HH * WW);
            float v = g0 * xc[i0] + g1 * xc[i1] + g2 * xc[i2] + g3 * xc[i3];
            vlds[c][w] = v;
        }
        __syncthreads();

        // accumulate: acc[j] (o = q*16+j) += vlds[c][w] * wt2[c][o]
#pragma unroll 4
        for (int c = 0; c < CG; ++c) {
            float xv = vlds[c][w];
#pragma unroll
            for (int j = 0; j < 16; ++j)
                acc[j] += xv * wt2[c][q * 16 + j];
        }
    }

#pragma unroll
    for (int j = 0; j < 16; ++j) {
        int o = q * 16 + j;
        out[(((size_t)b * CIN + g * CG + o) * HH + h) * WW + w] =
            acc[j] + b_def[g * CG + o];
    }
}

extern "C" void kernel_launch(void* const* d_in, const int* in_sizes, int n_in,
                              void* d_out, int out_size, void* d_ws, size_t ws_size,
                              hipStream_t stream) {
    const float* x     = (const float*)d_in[0];
    const float* w_off = (const float*)d_in[1];
    const float* b_off = (const float*)d_in[2];
    const float* w_def = (const float*)d_in[3];
    const float* b_def = (const float*)d_in[4];
    float* out  = (float*)d_out;
    float* offs = (float*)d_ws;   // B*72*H*W fp32 = 9.4 MB scratch

    conv_off_kernel<<<BATCH * HH, 256, 0, stream>>>(x, w_off, b_off, offs);
    deform_kernel<<<BATCH * OG * HH, 256, 0, stream>>>(x, offs, w_def, b_def, out);
}

// Round 2
// 729.744 us; speedup vs baseline: 1.3460x; 1.3460x over previous
//
#include <hip/hip_runtime.h>
#include <hip/hip_bf16.h>

// Problem constants (B=8, C=256, H=W=64, OG=4, Cg=64, K=9, C_off=72)
#define BATCH 8
#define CIN   256
#define HH    64
#define WW    64
#define HW    4096
#define OG    4
#define CG    64
#define COFF  72
#define CK2   16   // input-channel chunk for conv1

typedef __attribute__((ext_vector_type(8))) short bf16x8;
typedef __attribute__((ext_vector_type(4))) float floatx4;

struct __align__(4) f2 { float x, y; };   // align-4 float2 (4B-aligned dwordx2 ok on gfx9+)

static __device__ __forceinline__ short f2bf(float f) {
    unsigned u = __builtin_bit_cast(unsigned, f);
    unsigned r = (u + 0x7FFFu + ((u >> 16) & 1u)) >> 16;   // RNE
    return (short)r;
}

// ws layout:
//   offs  fp32  [B][72][H][W]              bytes [0, 9437184)
//   wT    bf16  [g][k][o][c] (4*9*64*64)   bytes [9437184, 9732096)
//   woT   fp32  [(c*9+tap)*80 + oc]        bytes [9732096, 10469376)
#define OFFS_ELEMS (BATCH * COFF * HH * WW)      // 2359296
#define WT_ELEMS   (OG * 9 * CG * CG)            // 147456
#define WOT_ELEMS  (CIN * 9 * 80)                // 184320

// ---------------------------------------------------------------------------
// Prep: transpose weights once per call.
//   wT[((g*9+k)*64 + o)*64 + c] = bf16(w_def[((g*64+o)*64 + c)*9 + k])
//   woT[(c*9+tap)*80 + oc]      = w_off[(oc*256+c)*9 + tap]  (oc<72, else 0)
// ---------------------------------------------------------------------------
__global__ __launch_bounds__(256) void prep_kernel(
    const float* __restrict__ w_def, const float* __restrict__ w_off,
    unsigned short* __restrict__ wT, float* __restrict__ woT)
{
    int i = blockIdx.x * 256 + threadIdx.x;
    if (i < WT_ELEMS) {
        int c = i & 63;
        int o = (i >> 6) & 63;
        int gk = i >> 12;          // 0..35
        int k = gk % 9, g = gk / 9;
        float v = w_def[((size_t)((g * CG + o) * CG + c)) * 9 + k];
        wT[i] = (unsigned short)f2bf(v);
    } else if (i < WT_ELEMS + WOT_ELEMS) {
        int j = i - WT_ELEMS;
        int oc = j % 80;
        int ct = j / 80;           // c*9 + tap
        int tap = ct % 9, c = ct / 9;
        woT[j] = (oc < COFF) ? w_off[((size_t)(oc * CIN + c)) * 9 + tap] : 0.f;
    }
}

// ---------------------------------------------------------------------------
// Kernel 1: offsets = conv3x3(x, w_off) + b_off
// grid = B*H, 256 threads. Weights come from woT via wave-uniform addresses
// (SGPR operands in the FMA) -> only 1 LDS read per 18 FMAs.
// ---------------------------------------------------------------------------
__global__ __launch_bounds__(256) void conv_off_kernel(
    const float* __restrict__ x, const float* __restrict__ woT,
    const float* __restrict__ b_off, float* __restrict__ offs)
{
    const int b = blockIdx.x >> 6;
    const int h = blockIdx.x & 63;
    const int t = threadIdx.x;
    const int w = t & 63;
    const int qu = __builtin_amdgcn_readfirstlane(t >> 6);  // wave-uniform

    __shared__ float xs[3][CK2][WW + 2];   // zero-padded input rows

    float acc[18];
#pragma unroll
    for (int j = 0; j < 18; ++j) acc[j] = 0.f;

    for (int c0 = 0; c0 < CIN; c0 += CK2) {
        __syncthreads();
        for (int i = t; i < 3 * CK2 * (WW + 2); i += 256) {
            int wp  = i % (WW + 2);
            int rem = i / (WW + 2);
            int cc  = rem % CK2;
            int ky  = rem / CK2;
            int yy  = h + ky - 1;
            int xx  = wp - 1;
            float v = 0.f;
            if (yy >= 0 && yy < HH && xx >= 0 && xx < WW)
                v = x[(((size_t)b * CIN + c0 + cc) * HH + yy) * WW + xx];
            xs[ky][cc][wp] = v;
        }
        __syncthreads();

        for (int tap = 0; tap < 9; ++tap) {
            const int ky = tap / 3, kx = tap % 3;
            for (int cc = 0; cc < CK2; ++cc) {
                float xv = xs[ky][cc][w + kx];
                const float* wp2 = woT + ((size_t)(c0 + cc) * 9 + tap) * 80 + qu * 18;
#pragma unroll
                for (int j = 0; j < 18; ++j)
                    acc[j] += xv * wp2[j];
            }
        }
    }
#pragma unroll
    for (int j = 0; j < 18; ++j) {
        int oc = qu * 18 + j;
        offs[(((size_t)b * COFF + oc) * HH + h) * WW + w] = acc[j] + b_off[oc];
    }
}

// ---------------------------------------------------------------------------
// Kernel 2: deformable conv via bf16 MFMA 16x16x32.
// grid = B*OG*H blocks, 256 threads = 4 waves.
// Wave wv owns N-tile (pixels wv*16..+15); lane l: pixel p = wv*16+(l&15).
// B-frags: each lane gathers its pixel's 16 channels (quad*8+j, +32) straight
// into registers (no LDS for V). A-frags: 8KB bf16 weight tile per tap in LDS
// (row-padded to 72 -> 2-way-free bank pattern), from pre-transposed wT.
// C/D: o = mt*16 + quad*4 + reg, pixel = wv*16 + (l&15).
// ---------------------------------------------------------------------------
__global__ __launch_bounds__(256) void deform_kernel(
    const float* __restrict__ x, const float* __restrict__ offs,
    const unsigned short* __restrict__ wT, const float* __restrict__ b_def,
    float* __restrict__ out)
{
    const int h  = blockIdx.x & 63;
    const int bg = blockIdx.x >> 6;
    const int g  = bg & 3;
    const int b  = bg >> 2;
    const int t  = threadIdx.x;
    const int wv = t >> 6;
    const int l  = t & 63;
    const int lane16 = l & 15;
    const int quad   = l >> 4;
    const int p = wv * 16 + lane16;   // this lane's pixel (w coordinate)

    __shared__ short wa[CG][72];      // bf16 weights [o][c], padded row

    floatx4 acc[4];
#pragma unroll
    for (int mt = 0; mt < 4; ++mt) acc[mt] = (floatx4){0.f, 0.f, 0.f, 0.f};

    const float* xg = x + (size_t)(b * CIN + g * CG) * HW;

    for (int k = 0; k < 9; ++k) {
        __syncthreads();   // protect wa from previous tap's readers
        // ---- stage A tile: 4096 bf16 (8 KB), 32 B per thread ----
        {
            const uint4* src = (const uint4*)(wT + ((size_t)(g * 9 + k) << 12)) + t * 2;
            uint4 d0 = src[0], d1 = src[1];
            int o = t >> 2, cc = (t & 3) << 4;
            uint4* dst = (uint4*)&wa[o][cc];
            dst[0] = d0; dst[1] = d1;
        }
        // ---- bilinear params for this lane's pixel ----
        const float* ofb = offs + (((size_t)(b * COFF + g * 18 + 2 * k)) * HH + h) * WW + p;
        float dy = ofb[0];
        float dx = ofb[HW];
        float py = dy + (float)(h + (k / 3) - 1);
        float px = dx + (float)(p + (k % 3) - 1);
        float y0f = floorf(py), x0f = floorf(px);
        float fy = py - y0f, fx = px - x0f;
        int y0 = (int)y0f, x0 = (int)x0f;
        bool vy0 = (y0 >= 0) & (y0 < HH);
        bool vy1 = (y0 >= -1) & (y0 < HH - 1);
        bool vx0 = (x0 >= 0) & (x0 < WW);
        bool vx1 = (x0 >= -1) & (x0 < WW - 1);
        float wy0 = vy0 ? (1.f - fy) : 0.f;
        float wy1 = vy1 ? fy : 0.f;
        float wx0 = vx0 ? (1.f - fx) : 0.f;
        float wx1 = vx1 ? fx : 0.f;
        int yia = min(max(y0, 0), HH - 1);
        int yib = min(max(y0 + 1, 0), HH - 1);
        int xia = min(max(x0, 0), WW - 1);
        int xib = min(max(x0 + 1, 0), WW - 1);
        int xbase = min(xia, WW - 2);
        bool sa = (xia != xbase);      // component selectors
        bool sb = (xib != xbase);
        int ra = yia * WW + xbase;
        int rb = yib * WW + xbase;

        // ---- gather 16 channels for this pixel into B-frags ----
        union { bf16x8 v; short s[8]; } f0, f1;
#pragma unroll
        for (int j = 0; j < 8; ++j) {
            int c = quad * 8 + j;
            {
                const float* xc = xg + (size_t)c * HW;
                f2 fa = *(const f2*)(xc + ra);
                f2 fb = *(const f2*)(xc + rb);
                float va0 = sa ? fa.y : fa.x;
                float va1 = sb ? fa.y : fa.x;
                float vb0 = sa ? fb.y : fb.x;
                float vb1 = sb ? fb.y : fb.x;
                float v = wy0 * (wx0 * va0 + wx1 * va1) + wy1 * (wx0 * vb0 + wx1 * vb1);
                f0.s[j] = f2bf(v);
            }
            {
                const float* xc = xg + (size_t)(c + 32) * HW;
                f2 fa = *(const f2*)(xc + ra);
                f2 fb = *(const f2*)(xc + rb);
                float va0 = sa ? fa.y : fa.x;
                float va1 = sb ? fa.y : fa.x;
                float vb0 = sa ? fb.y : fb.x;
                float vb1 = sb ? fb.y : fb.x;
                float v = wy0 * (wx0 * va0 + wx1 * va1) + wy1 * (wx0 * vb0 + wx1 * vb1);
                f1.s[j] = f2bf(v);
            }
        }
        __syncthreads();   // wa staged

        // ---- MFMA: 4 M-tiles x 2 K-steps ----
#pragma unroll
        for (int mt = 0; mt < 4; ++mt) {
            bf16x8 a0 = *(const bf16x8*)&wa[mt * 16 + lane16][quad * 8];
            bf16x8 a1 = *(const bf16x8*)&wa[mt * 16 + lane16][32 + quad * 8];
            acc[mt] = __builtin_amdgcn_mfma_f32_16x16x32_bf16(a0, f0.v, acc[mt], 0, 0, 0);
            acc[mt] = __builtin_amdgcn_mfma_f32_16x16x32_bf16(a1, f1.v, acc[mt], 0, 0, 0);
        }
    }

    // ---- epilogue ----
#pragma unroll
    for (int mt = 0; mt < 4; ++mt) {
#pragma unroll
        for (int r = 0; r < 4; ++r) {
            int o = mt * 16 + quad * 4 + r;
            float v = acc[mt][r] + b_def[g * CG + o];
            out[((size_t)(b * CIN + g * CG + o) * HH + h) * WW + p] = v;
        }
    }
}

extern "C" void kernel_launch(void* const* d_in, const int* in_sizes, int n_in,
                              void* d_out, int out_size, void* d_ws, size_t ws_size,
                              hipStream_t stream) {
    const float* x     = (const float*)d_in[0];
    const float* w_off = (const float*)d_in[1];
    const float* b_off = (const float*)d_in[2];
    const float* w_def = (const float*)d_in[3];
    const float* b_def = (const float*)d_in[4];
    float* out = (float*)d_out;

    char* ws = (char*)d_ws;
    float*          offs = (float*)ws;                                  // 9.44 MB
    unsigned short* wT   = (unsigned short*)(ws + (size_t)OFFS_ELEMS * 4);
    float*          woT  = (float*)(ws + (size_t)OFFS_ELEMS * 4 + (size_t)WT_ELEMS * 2);

    int prep_elems = WT_ELEMS + WOT_ELEMS;
    prep_kernel<<<(prep_elems + 255) / 256, 256, 0, stream>>>(w_def, w_off, wT, woT);
    conv_off_kernel<<<BATCH * HH, 256, 0, stream>>>(x, woT, b_off, offs);
    deform_kernel<<<BATCH * OG * HH, 256, 0, stream>>>(x, offs, wT, b_def, out);
}

// Round 3
// 371.658 us; speedup vs baseline: 2.6429x; 1.9635x over previous
//
#include <hip/hip_runtime.h>
#include <hip/hip_bf16.h>

// Problem constants (B=8, C=256, H=W=64, OG=4, Cg=64, K=9, C_off=72)
#define BATCH 8
#define CIN   256
#define HH    64
#define WW    64
#define HW    4096
#define OG    4
#define CG    64
#define COFF  72

typedef __attribute__((ext_vector_type(8))) short bf16x8;
typedef __attribute__((ext_vector_type(4))) float floatx4;

struct __align__(4) f2 { float x, y; };   // align-4 float2

static __device__ __forceinline__ short f2bf(float f) {
    unsigned u = __builtin_bit_cast(unsigned, f);
    unsigned r = (u + 0x7FFFu + ((u >> 16) & 1u)) >> 16;   // RNE
    return (short)r;
}

// ws layout:
//   offs  fp32  [B][72][H][W]                      bytes [0, 9437184)
//   wT    bf16  [g][k][o][c]      (4*9*64*64)      bytes [9437184, 9732096)
//   woT2  bf16  [(chunk*9+tap)*80 + oc]*32 + cc    bytes [9732096, 10100736)
#define OFFS_ELEMS (BATCH * COFF * HH * WW)      // 2359296
#define WT_ELEMS   (OG * 9 * CG * CG)            // 147456
#define WO2_ELEMS  (8 * 9 * 80 * 32)             // 184320

// ---------------------------------------------------------------------------
// Prep: transpose weights once per call.
//   wT  [((g*9+k)*64 + o)*64 + c]      = bf16(w_def[((g*64+o)*64 + c)*9 + k])
//   woT2[((chunk*9+tap)*80 + oc)*32+cc] = bf16(w_off[(oc*256 + chunk*32+cc)*9 + tap]), 0 if oc>=72
// ---------------------------------------------------------------------------
__global__ __launch_bounds__(256) void prep_kernel(
    const float* __restrict__ w_def, const float* __restrict__ w_off,
    unsigned short* __restrict__ wT, unsigned short* __restrict__ woT2)
{
    int i = blockIdx.x * 256 + threadIdx.x;
    if (i < WT_ELEMS) {
        int c = i & 63;
        int o = (i >> 6) & 63;
        int gk = i >> 12;          // 0..35
        int k = gk % 9, g = gk / 9;
        float v = w_def[((size_t)((g * CG + o) * CG + c)) * 9 + k];
        wT[i] = (unsigned short)f2bf(v);
    } else if (i < WT_ELEMS + WO2_ELEMS) {
        int j = i - WT_ELEMS;
        int cc = j & 31;
        int oc = (j >> 5) % 80;
        int ct = (j >> 5) / 80;    // chunk*9 + tap
        int tap = ct % 9, chunk = ct / 9;
        float v = 0.f;
        if (oc < COFF)
            v = w_off[((size_t)(oc * CIN + chunk * 32 + cc)) * 9 + tap];
        woT2[j] = (unsigned short)f2bf(v);
    }
}

// ---------------------------------------------------------------------------
// Kernel 1: offsets = conv3x3(x, w_off) + b_off  -- implicit-GEMM bf16 MFMA.
// grid = B*H, 256 threads = 4 waves; wave wv owns pixels wv*16..+15.
// M = 80 (72 padded) -> 5 M-tiles; K = 2304 = 8 chunks x 9 taps x 32 ch.
// Per chunk: stage 3 rows x 32 ch of x as bf16 in LDS [ky][wp(66)][cc(pad 40)]
// (channel-contiguous, 16B-aligned b128 reads). A-frags straight from global
// woT2 (L1-hot, dwordx4). 45 MFMA per chunk per wave.
// ---------------------------------------------------------------------------
__global__ __launch_bounds__(256) void conv_off_kernel(
    const float* __restrict__ x, const unsigned short* __restrict__ woT2,
    const float* __restrict__ b_off, float* __restrict__ offs)
{
    const int b = blockIdx.x >> 6;
    const int h = blockIdx.x & 63;
    const int t = threadIdx.x;
    const int wv = t >> 6;
    const int l  = t & 63;
    const int lane16 = l & 15;
    const int quad   = l >> 4;
    const int p = wv * 16 + lane16;

    __shared__ short xs[3][66][40];   // [ky][pixel+1][cc] pad 40: b128-aligned

    floatx4 acc[5];
#pragma unroll
    for (int mt = 0; mt < 5; ++mt) acc[mt] = (floatx4){0.f, 0.f, 0.f, 0.f};

    for (int chunk = 0; chunk < 8; ++chunk) {
        __syncthreads();
        // stage x rows (zero-padded in h and w), bf16, transposed to [row][pix][c]
        for (int i = t; i < 3 * 66 * 32; i += 256) {
            int wp  = i % 66;
            int rem = i / 66;
            int cc  = rem & 31;
            int ky  = rem >> 5;
            int yy = h + ky - 1;
            int xx = wp - 1;
            float v = 0.f;
            if (yy >= 0 && yy < HH && xx >= 0 && xx < WW)
                v = x[((size_t)(b * CIN + chunk * 32 + cc) << 12) + (yy << 6) + xx];
            xs[ky][wp][cc] = f2bf(v);
        }
        __syncthreads();

#pragma unroll
        for (int tap = 0; tap < 9; ++tap) {
            const int ky = tap / 3, kx = tap % 3;
            bf16x8 bfrag = *(const bf16x8*)&xs[ky][p + kx][quad * 8];
            const unsigned short* abase =
                woT2 + ((size_t)(chunk * 9 + tap) * 80) * 32 + quad * 8;
#pragma unroll
            for (int mt = 0; mt < 5; ++mt) {
                bf16x8 afrag = *(const bf16x8*)(abase + (mt * 16 + lane16) * 32);
                acc[mt] = __builtin_amdgcn_mfma_f32_16x16x32_bf16(afrag, bfrag, acc[mt], 0, 0, 0);
            }
        }
    }

#pragma unroll
    for (int mt = 0; mt < 5; ++mt) {
#pragma unroll
        for (int r = 0; r < 4; ++r) {
            int oc = mt * 16 + quad * 4 + r;
            if (oc < COFF)
                offs[((size_t)(b * COFF + oc) << 12) + (h << 6) + p] =
                    acc[mt][r] + b_off[oc];
        }
    }
}

// ---------------------------------------------------------------------------
// Kernel 2: deformable conv via bf16 MFMA 16x16x32 (verified layout).
// grid = B*OG*H blocks, 256 threads = 4 waves. Offsets for all 9 taps are
// prefetched into registers up front (kills the per-tap dependent HBM load).
// ---------------------------------------------------------------------------
__global__ __launch_bounds__(256) void deform_kernel(
    const float* __restrict__ x, const float* __restrict__ offs,
    const unsigned short* __restrict__ wT, const float* __restrict__ b_def,
    float* __restrict__ out)
{
    const int h  = blockIdx.x & 63;
    const int bg = blockIdx.x >> 6;
    const int g  = bg & 3;
    const int b  = bg >> 2;
    const int t  = threadIdx.x;
    const int wv = t >> 6;
    const int l  = t & 63;
    const int lane16 = l & 15;
    const int quad   = l >> 4;
    const int p = wv * 16 + lane16;   // this lane's pixel (w coordinate)

    __shared__ short wa[CG][72];      // bf16 weights [o][c], padded row

    floatx4 acc[4];
#pragma unroll
    for (int mt = 0; mt < 4; ++mt) acc[mt] = (floatx4){0.f, 0.f, 0.f, 0.f};

    const float* xg = x + (size_t)(b * CIN + g * CG) * HW;

    // ---- prefetch all 18 offset values for this pixel ----
    float dyv[9], dxv[9];
    {
        const float* ofb = offs + (((size_t)(b * COFF + g * 18)) * HH + h) * WW + p;
#pragma unroll
        for (int k = 0; k < 9; ++k) {
            dyv[k] = ofb[(size_t)(2 * k) * HW];
            dxv[k] = ofb[(size_t)(2 * k + 1) * HW];
        }
    }

    for (int k = 0; k < 9; ++k) {
        __syncthreads();   // protect wa from previous tap's readers
        // ---- stage A tile: 4096 bf16 (8 KB), 32 B per thread ----
        {
            const uint4* src = (const uint4*)(wT + ((size_t)(g * 9 + k) << 12)) + t * 2;
            uint4 d0 = src[0], d1 = src[1];
            int o = t >> 2, cc = (t & 3) << 4;
            uint4* dst = (uint4*)&wa[o][cc];
            dst[0] = d0; dst[1] = d1;
        }
        // ---- bilinear params for this lane's pixel ----
        float py = dyv[k] + (float)(h + (k / 3) - 1);
        float px = dxv[k] + (float)(p + (k % 3) - 1);
        float y0f = floorf(py), x0f = floorf(px);
        float fy = py - y0f, fx = px - x0f;
        int y0 = (int)y0f, x0 = (int)x0f;
        bool vy0 = (y0 >= 0) & (y0 < HH);
        bool vy1 = (y0 >= -1) & (y0 < HH - 1);
        bool vx0 = (x0 >= 0) & (x0 < WW);
        bool vx1 = (x0 >= -1) & (x0 < WW - 1);
        float wy0 = vy0 ? (1.f - fy) : 0.f;
        float wy1 = vy1 ? fy : 0.f;
        float wx0 = vx0 ? (1.f - fx) : 0.f;
        float wx1 = vx1 ? fx : 0.f;
        int yia = min(max(y0, 0), HH - 1);
        int yib = min(max(y0 + 1, 0), HH - 1);
        int xia = min(max(x0, 0), WW - 1);
        int xib = min(max(x0 + 1, 0), WW - 1);
        int xbase = min(xia, WW - 2);
        bool sa = (xia != xbase);      // component selectors
        bool sb = (xib != xbase);
        int ra = yia * WW + xbase;
        int rb = yib * WW + xbase;

        // ---- gather 16 channels for this pixel into B-frags ----
        union { bf16x8 v; short s[8]; } f0, f1;
#pragma unroll
        for (int j = 0; j < 8; ++j) {
            int c = quad * 8 + j;
            {
                const float* xc = xg + (size_t)c * HW;
                f2 fa = *(const f2*)(xc + ra);
                f2 fb = *(const f2*)(xc + rb);
                float va0 = sa ? fa.y : fa.x;
                float va1 = sb ? fa.y : fa.x;
                float vb0 = sa ? fb.y : fb.x;
                float vb1 = sb ? fb.y : fb.x;
                float v = wy0 * (wx0 * va0 + wx1 * va1) + wy1 * (wx0 * vb0 + wx1 * vb1);
                f0.s[j] = f2bf(v);
            }
            {
                const float* xc = xg + (size_t)(c + 32) * HW;
                f2 fa = *(const f2*)(xc + ra);
                f2 fb = *(const f2*)(xc + rb);
                float va0 = sa ? fa.y : fa.x;
                float va1 = sb ? fa.y : fa.x;
                float vb0 = sa ? fb.y : fb.x;
                float vb1 = sb ? fb.y : fb.x;
                float v = wy0 * (wx0 * va0 + wx1 * va1) + wy1 * (wx0 * vb0 + wx1 * vb1);
                f1.s[j] = f2bf(v);
            }
        }
        __syncthreads();   // wa staged

        // ---- MFMA: 4 M-tiles x 2 K-steps ----
#pragma unroll
        for (int mt = 0; mt < 4; ++mt) {
            bf16x8 a0 = *(const bf16x8*)&wa[mt * 16 + lane16][quad * 8];
            bf16x8 a1 = *(const bf16x8*)&wa[mt * 16 + lane16][32 + quad * 8];
            acc[mt] = __builtin_amdgcn_mfma_f32_16x16x32_bf16(a0, f0.v, acc[mt], 0, 0, 0);
            acc[mt] = __builtin_amdgcn_mfma_f32_16x16x32_bf16(a1, f1.v, acc[mt], 0, 0, 0);
        }
    }

    // ---- epilogue ----
#pragma unroll
    for (int mt = 0; mt < 4; ++mt) {
#pragma unroll
        for (int r = 0; r < 4; ++r) {
            int o = mt * 16 + quad * 4 + r;
            float v = acc[mt][r] + b_def[g * CG + o];
            out[((size_t)(b * CIN + g * CG + o) * HH + h) * WW + p] = v;
        }
    }
}

extern "C" void kernel_launch(void* const* d_in, const int* in_sizes, int n_in,
                              void* d_out, int out_size, void* d_ws, size_t ws_size,
                              hipStream_t stream) {
    const float* x     = (const float*)d_in[0];
    const float* w_off = (const float*)d_in[1];
    const float* b_off = (const float*)d_in[2];
    const float* w_def = (const float*)d_in[3];
    const float* b_def = (const float*)d_in[4];
    float* out = (float*)d_out;

    char* ws = (char*)d_ws;
    float*          offs = (float*)ws;                                   // 9.44 MB
    unsigned short* wT   = (unsigned short*)(ws + (size_t)OFFS_ELEMS * 4);
    unsigned short* woT2 = (unsigned short*)(ws + (size_t)OFFS_ELEMS * 4 + (size_t)WT_ELEMS * 2);

    int prep_elems = WT_ELEMS + WO2_ELEMS;
    prep_kernel<<<(prep_elems + 255) / 256, 256, 0, stream>>>(w_def, w_off, wT, woT2);
    conv_off_kernel<<<BATCH * HH, 256, 0, stream>>>(x, woT2, b_off, offs);
    deform_kernel<<<BATCH * OG * HH, 256, 0, stream>>>(x, offs, wT, b_def, out);
}

// Round 4
// 288.702 us; speedup vs baseline: 3.4024x; 1.2873x over previous
//
#include <hip/hip_runtime.h>
#include <hip/hip_bf16.h>

// Problem constants (B=8, C=256, H=W=64, OG=4, Cg=64, K=9, C_off=72)
#define BATCH 8
#define CIN   256
#define HH    64
#define WW    64
#define HW    4096
#define OG    4
#define CG    64
#define COFF  72

typedef __attribute__((ext_vector_type(8))) short bf16x8;
typedef __attribute__((ext_vector_type(4))) float floatx4;

struct __align__(4) f2 { float x, y; };   // align-4 float2 (fallback path)

static __device__ __forceinline__ short f2bf(float f) {
    unsigned u = __builtin_bit_cast(unsigned, f);
    unsigned r = (u + 0x7FFFu + ((u >> 16) & 1u)) >> 16;   // RNE
    return (short)r;
}
static __device__ __forceinline__ float b2f(unsigned short u) {
    return __builtin_bit_cast(float, ((unsigned)u) << 16);
}

// ws layout:
//   offs  fp32  [B][72][H][W]                       bytes [0, 9437184)
//   wT    bf16  [g][k][o][c]        (4*9*64*64)     bytes [9437184, 9732096)
//   woT2  bf16  [((chunk*9+tap)*80+oc)*32+cc]       bytes [9732096, 10100736)
//   xbf   bf16  [b][y][x][c]  NHWC  (8*4096*256)    bytes [10100736, 26877952)
#define OFFS_ELEMS (BATCH * COFF * HH * WW)      // 2359296
#define WT_ELEMS   (OG * 9 * CG * CG)            // 147456
#define WO2_ELEMS  (8 * 9 * 80 * 32)             // 184320
#define XBF_BYTE_OFF ((size_t)OFFS_ELEMS * 4 + (size_t)WT_ELEMS * 2 + (size_t)WO2_ELEMS * 2)
#define NEED_NHWC (XBF_BYTE_OFF + (size_t)BATCH * HW * CIN * 2)   // 26877952

// ---------------------------------------------------------------------------
// Prep A: transpose weights (both convs) once per call.
// ---------------------------------------------------------------------------
__global__ __launch_bounds__(256) void prep_w_kernel(
    const float* __restrict__ w_def, const float* __restrict__ w_off,
    unsigned short* __restrict__ wT, unsigned short* __restrict__ woT2)
{
    int i = blockIdx.x * 256 + threadIdx.x;
    if (i < WT_ELEMS) {
        int c = i & 63;
        int o = (i >> 6) & 63;
        int gk = i >> 12;          // 0..35
        int k = gk % 9, g = gk / 9;
        float v = w_def[((size_t)((g * CG + o) * CG + c)) * 9 + k];
        wT[i] = (unsigned short)f2bf(v);
    } else if (i < WT_ELEMS + WO2_ELEMS) {
        int j = i - WT_ELEMS;
        int cc = j & 31;
        int oc = (j >> 5) % 80;
        int ct = (j >> 5) / 80;    // chunk*9 + tap
        int tap = ct % 9, chunk = ct / 9;
        float v = 0.f;
        if (oc < COFF)
            v = w_off[((size_t)(oc * CIN + chunk * 32 + cc)) * 9 + tap];
        woT2[j] = (unsigned short)f2bf(v);
    }
}

// ---------------------------------------------------------------------------
// Prep B: x NCHW fp32 -> NHWC bf16.  grid = B*H blocks, one (b,y) row each.
// Phase 1: coalesced float4 reads (4 px per lane), b16 LDS writes (2-way ok).
// Phase 2: 4x b32 LDS reads -> fully coalesced dwordx4 global stores.
// ---------------------------------------------------------------------------
__global__ __launch_bounds__(256) void prep_x_kernel(
    const float* __restrict__ x, unsigned short* __restrict__ xbf)
{
    const int b = blockIdx.x >> 6;
    const int y = blockIdx.x & 63;
    const int t = threadIdx.x;

    __shared__ short tile[64][258];   // [px][c], pad 258 keeps b16 writes 2-way

#pragma unroll
    for (int it = 0; it < 16; ++it) {
        int i  = t + it * 256;        // i < 4096
        int c  = i >> 4;
        int p4 = (i & 15) << 2;
        float4 v = *(const float4*)(x + (((size_t)(b * CIN + c)) << 12) + (y << 6) + p4);
        tile[p4 + 0][c] = f2bf(v.x);
        tile[p4 + 1][c] = f2bf(v.y);
        tile[p4 + 2][c] = f2bf(v.z);
        tile[p4 + 3][c] = f2bf(v.w);
    }
    __syncthreads();

    unsigned short* dst = xbf + (((size_t)(b * HW)) << 8) + ((size_t)(y * WW) << 8);
#pragma unroll
    for (int k = 0; k < 8; ++k) {
        int i  = t + k * 256;         // i < 2048
        int p  = i >> 5;
        int c8 = (i & 31) << 3;
        const unsigned* tp = (const unsigned*)&tile[p][c8];
        uint4 r = make_uint4(tp[0], tp[1], tp[2], tp[3]);
        *(uint4*)(dst + ((size_t)p << 8) + c8) = r;
    }
}

// ---------------------------------------------------------------------------
// Kernel 1 (NHWC): offsets = conv3x3(x) + b_off. Implicit-GEMM bf16 MFMA.
// grid = B*H, 256 threads = 4 waves. NO LDS, NO barriers: B-frag is one 16B
// global load from xbf (L1-resident chunk footprint), A-frags from woT2.
// ---------------------------------------------------------------------------
__global__ __launch_bounds__(256) void conv_off_nhwc(
    const unsigned short* __restrict__ xbf, const unsigned short* __restrict__ woT2,
    const float* __restrict__ b_off, float* __restrict__ offs)
{
    const int b = blockIdx.x >> 6;
    const int h = blockIdx.x & 63;
    const int t = threadIdx.x;
    const int wv = t >> 6;
    const int l  = t & 63;
    const int lane16 = l & 15;
    const int quad   = l >> 4;
    const int p = wv * 16 + lane16;

    floatx4 acc[5];
#pragma unroll
    for (int mt = 0; mt < 5; ++mt) acc[mt] = (floatx4){0.f, 0.f, 0.f, 0.f};

    const unsigned short* xb = xbf + (((size_t)(b * HW)) << 8);

    for (int chunk = 0; chunk < 8; ++chunk) {
#pragma unroll
        for (int tap = 0; tap < 9; ++tap) {
            const int ky = tap / 3, kx = tap % 3;
            const int yy = h + ky - 1;
            const int xx = p + kx - 1;
            bf16x8 bfrag = (bf16x8)0;
            if ((unsigned)yy < 64u && (unsigned)xx < 64u)
                bfrag = *(const bf16x8*)(xb + (((size_t)((yy << 6) + xx)) << 8)
                                            + chunk * 32 + quad * 8);
            const unsigned short* abase =
                woT2 + ((size_t)(chunk * 9 + tap) * 80) * 32 + quad * 8;
#pragma unroll
            for (int mt = 0; mt < 5; ++mt) {
                bf16x8 afrag = *(const bf16x8*)(abase + (mt * 16 + lane16) * 32);
                acc[mt] = __builtin_amdgcn_mfma_f32_16x16x32_bf16(afrag, bfrag, acc[mt], 0, 0, 0);
            }
        }
    }

#pragma unroll
    for (int mt = 0; mt < 5; ++mt) {
#pragma unroll
        for (int r = 0; r < 4; ++r) {
            int oc = mt * 16 + quad * 4 + r;
            if (oc < COFF)
                offs[((size_t)(b * COFF + oc) << 12) + (h << 6) + p] =
                    acc[mt][r] + b_off[oc];
        }
    }
}

// ---------------------------------------------------------------------------
// Kernel 2 (NHWC): deformable conv via bf16 MFMA. NO LDS, NO barriers.
// Per tap: 8x16B gathers (4 corners x 2 halves of 64ch), bilinear blend in
// fp32, A-frags straight from global wT (L1/L2-hot), 8 MFMAs.
// ---------------------------------------------------------------------------
__global__ __launch_bounds__(256) void deform_nhwc(
    const unsigned short* __restrict__ xbf, const float* __restrict__ offs,
    const unsigned short* __restrict__ wT, const float* __restrict__ b_def,
    float* __restrict__ out)
{
    const int h  = blockIdx.x & 63;
    const int bg = blockIdx.x >> 6;
    const int g  = bg & 3;
    const int b  = bg >> 2;
    const int t  = threadIdx.x;
    const int wv = t >> 6;
    const int l  = t & 63;
    const int lane16 = l & 15;
    const int quad   = l >> 4;
    const int p = wv * 16 + lane16;

    floatx4 acc[4];
#pragma unroll
    for (int mt = 0; mt < 4; ++mt) acc[mt] = (floatx4){0.f, 0.f, 0.f, 0.f};

    // prefetch all 18 offset values for this pixel
    float dyv[9], dxv[9];
    {
        const float* ofb = offs + (((size_t)(b * COFF + g * 18)) * HH + h) * WW + p;
#pragma unroll
        for (int k = 0; k < 9; ++k) {
            dyv[k] = ofb[(size_t)(2 * k) * HW];
            dxv[k] = ofb[(size_t)(2 * k + 1) * HW];
        }
    }

    const unsigned short* xb = xbf + (((size_t)(b * HW)) << 8) + g * 64;

#pragma unroll
    for (int k = 0; k < 9; ++k) {
        // ---- bilinear params ----
        float py = dyv[k] + (float)(h + (k / 3) - 1);
        float px = dxv[k] + (float)(p + (k % 3) - 1);
        float y0f = floorf(py), x0f = floorf(px);
        float fy = py - y0f, fx = px - x0f;
        int y0 = (int)y0f, x0 = (int)x0f;
        float wy0 = ((y0 >= 0) & (y0 < HH)) ? (1.f - fy) : 0.f;
        float wy1 = ((y0 >= -1) & (y0 < HH - 1)) ? fy : 0.f;
        float wx0 = ((x0 >= 0) & (x0 < WW)) ? (1.f - fx) : 0.f;
        float wx1 = ((x0 >= -1) & (x0 < WW - 1)) ? fx : 0.f;
        float w00 = wy0 * wx0, w01 = wy0 * wx1, w10 = wy1 * wx0, w11 = wy1 * wx1;
        int yia = min(max(y0, 0), HH - 1);
        int yib = min(max(y0 + 1, 0), HH - 1);
        int xia = min(max(x0, 0), WW - 1);
        int xib = min(max(x0 + 1, 0), WW - 1);
        size_t iaa = ((size_t)((yia << 6) + xia)) << 8;
        size_t iab = ((size_t)((yia << 6) + xib)) << 8;
        size_t iba = ((size_t)((yib << 6) + xia)) << 8;
        size_t ibb = ((size_t)((yib << 6) + xib)) << 8;

        // ---- gather: 4 corners x 2 channel-halves, 16B each ----
        const int co = quad * 8;
        union { bf16x8 v; unsigned short s[8]; } aaL, abL, baL, bbL, aaH, abH, baH, bbH;
        aaL.v = *(const bf16x8*)(xb + iaa + co);
        abL.v = *(const bf16x8*)(xb + iab + co);
        baL.v = *(const bf16x8*)(xb + iba + co);
        bbL.v = *(const bf16x8*)(xb + ibb + co);
        aaH.v = *(const bf16x8*)(xb + iaa + co + 32);
        abH.v = *(const bf16x8*)(xb + iab + co + 32);
        baH.v = *(const bf16x8*)(xb + iba + co + 32);
        bbH.v = *(const bf16x8*)(xb + ibb + co + 32);

        union { bf16x8 v; unsigned short s[8]; } f0, f1;
#pragma unroll
        for (int j = 0; j < 8; ++j) {
            float v0 = w00 * b2f(aaL.s[j]) + w01 * b2f(abL.s[j])
                     + w10 * b2f(baL.s[j]) + w11 * b2f(bbL.s[j]);
            float v1 = w00 * b2f(aaH.s[j]) + w01 * b2f(abH.s[j])
                     + w10 * b2f(baH.s[j]) + w11 * b2f(bbH.s[j]);
            f0.s[j] = (unsigned short)f2bf(v0);
            f1.s[j] = (unsigned short)f2bf(v1);
        }

        // ---- A-frags from global wT + MFMA ----
        const unsigned short* wk = wT + (((size_t)(g * 9 + k)) << 12);
#pragma unroll
        for (int mt = 0; mt < 4; ++mt) {
            bf16x8 a0 = *(const bf16x8*)(wk + (mt * 16 + lane16) * 64 + co);
            bf16x8 a1 = *(const bf16x8*)(wk + (mt * 16 + lane16) * 64 + 32 + co);
            acc[mt] = __builtin_amdgcn_mfma_f32_16x16x32_bf16(a0, f0.v, acc[mt], 0, 0, 0);
            acc[mt] = __builtin_amdgcn_mfma_f32_16x16x32_bf16(a1, f1.v, acc[mt], 0, 0, 0);
        }
    }

#pragma unroll
    for (int mt = 0; mt < 4; ++mt) {
#pragma unroll
        for (int r = 0; r < 4; ++r) {
            int o = mt * 16 + quad * 4 + r;
            float v = acc[mt][r] + b_def[g * CG + o];
            out[((size_t)(b * CIN + g * CG + o) * HH + h) * WW + p] = v;
        }
    }
}

// ===========================================================================
// FALLBACK PATH (ws too small for xbf): round-3 kernels, unchanged.
// ===========================================================================
__global__ __launch_bounds__(256) void conv_off_fb(
    const float* __restrict__ x, const unsigned short* __restrict__ woT2,
    const float* __restrict__ b_off, float* __restrict__ offs)
{
    const int b = blockIdx.x >> 6;
    const int h = blockIdx.x & 63;
    const int t = threadIdx.x;
    const int wv = t >> 6;
    const int l  = t & 63;
    const int lane16 = l & 15;
    const int quad   = l >> 4;
    const int p = wv * 16 + lane16;

    __shared__ short xs[3][66][40];

    floatx4 acc[5];
#pragma unroll
    for (int mt = 0; mt < 5; ++mt) acc[mt] = (floatx4){0.f, 0.f, 0.f, 0.f};

    for (int chunk = 0; chunk < 8; ++chunk) {
        __syncthreads();
        for (int i = t; i < 3 * 66 * 32; i += 256) {
            int wp  = i % 66;
            int rem = i / 66;
            int cc  = rem & 31;
            int ky  = rem >> 5;
            int yy = h + ky - 1;
            int xx = wp - 1;
            float v = 0.f;
            if (yy >= 0 && yy < HH && xx >= 0 && xx < WW)
                v = x[((size_t)(b * CIN + chunk * 32 + cc) << 12) + (yy << 6) + xx];
            xs[ky][wp][cc] = f2bf(v);
        }
        __syncthreads();

#pragma unroll
        for (int tap = 0; tap < 9; ++tap) {
            const int ky = tap / 3, kx = tap % 3;
            bf16x8 bfrag = *(const bf16x8*)&xs[ky][p + kx][quad * 8];
            const unsigned short* abase =
                woT2 + ((size_t)(chunk * 9 + tap) * 80) * 32 + quad * 8;
#pragma unroll
            for (int mt = 0; mt < 5; ++mt) {
                bf16x8 afrag = *(const bf16x8*)(abase + (mt * 16 + lane16) * 32);
                acc[mt] = __builtin_amdgcn_mfma_f32_16x16x32_bf16(afrag, bfrag, acc[mt], 0, 0, 0);
            }
        }
    }

#pragma unroll
    for (int mt = 0; mt < 5; ++mt) {
#pragma unroll
        for (int r = 0; r < 4; ++r) {
            int oc = mt * 16 + quad * 4 + r;
            if (oc < COFF)
                offs[((size_t)(b * COFF + oc) << 12) + (h << 6) + p] =
                    acc[mt][r] + b_off[oc];
        }
    }
}

__global__ __launch_bounds__(256) void deform_fb(
    const float* __restrict__ x, const float* __restrict__ offs,
    const unsigned short* __restrict__ wT, const float* __restrict__ b_def,
    float* __restrict__ out)
{
    const int h  = blockIdx.x & 63;
    const int bg = blockIdx.x >> 6;
    const int g  = bg & 3;
    const int b  = bg >> 2;
    const int t  = threadIdx.x;
    const int wv = t >> 6;
    const int l  = t & 63;
    const int lane16 = l & 15;
    const int quad   = l >> 4;
    const int p = wv * 16 + lane16;

    __shared__ short wa[CG][72];

    floatx4 acc[4];
#pragma unroll
    for (int mt = 0; mt < 4; ++mt) acc[mt] = (floatx4){0.f, 0.f, 0.f, 0.f};

    const float* xg = x + (size_t)(b * CIN + g * CG) * HW;

    float dyv[9], dxv[9];
    {
        const float* ofb = offs + (((size_t)(b * COFF + g * 18)) * HH + h) * WW + p;
#pragma unroll
        for (int k = 0; k < 9; ++k) {
            dyv[k] = ofb[(size_t)(2 * k) * HW];
            dxv[k] = ofb[(size_t)(2 * k + 1) * HW];
        }
    }

    for (int k = 0; k < 9; ++k) {
        __syncthreads();
        {
            const uint4* src = (const uint4*)(wT + ((size_t)(g * 9 + k) << 12)) + t * 2;
            uint4 d0 = src[0], d1 = src[1];
            int o = t >> 2, cc = (t & 3) << 4;
            uint4* dst = (uint4*)&wa[o][cc];
            dst[0] = d0; dst[1] = d1;
        }
        float py = dyv[k] + (float)(h + (k / 3) - 1);
        float px = dxv[k] + (float)(p + (k % 3) - 1);
        float y0f = floorf(py), x0f = floorf(px);
        float fy = py - y0f, fx = px - x0f;
        int y0 = (int)y0f, x0 = (int)x0f;
        float wy0 = ((y0 >= 0) & (y0 < HH)) ? (1.f - fy) : 0.f;
        float wy1 = ((y0 >= -1) & (y0 < HH - 1)) ? fy : 0.f;
        float wx0 = ((x0 >= 0) & (x0 < WW)) ? (1.f - fx) : 0.f;
        float wx1 = ((x0 >= -1) & (x0 < WW - 1)) ? fx : 0.f;
        int yia = min(max(y0, 0), HH - 1);
        int yib = min(max(y0 + 1, 0), HH - 1);
        int xia = min(max(x0, 0), WW - 1);
        int xib = min(max(x0 + 1, 0), WW - 1);
        int xbase = min(xia, WW - 2);
        bool sa = (xia != xbase);
        bool sb = (xib != xbase);
        int ra = yia * WW + xbase;
        int rb = yib * WW + xbase;

        union { bf16x8 v; short s[8]; } f0, f1;
#pragma unroll
        for (int j = 0; j < 8; ++j) {
            int c = quad * 8 + j;
            {
                const float* xc = xg + (size_t)c * HW;
                f2 fa = *(const f2*)(xc + ra);
                f2 fb = *(const f2*)(xc + rb);
                float va0 = sa ? fa.y : fa.x;
                float va1 = sb ? fa.y : fa.x;
                float vb0 = sa ? fb.y : fb.x;
                float vb1 = sb ? fb.y : fb.x;
                float v = wy0 * (wx0 * va0 + wx1 * va1) + wy1 * (wx0 * vb0 + wx1 * vb1);
                f0.s[j] = f2bf(v);
            }
            {
                const float* xc = xg + (size_t)(c + 32) * HW;
                f2 fa = *(const f2*)(xc + ra);
                f2 fb = *(const f2*)(xc + rb);
                float va0 = sa ? fa.y : fa.x;
                float va1 = sb ? fa.y : fa.x;
                float vb0 = sa ? fb.y : fb.x;
                float vb1 = sb ? fb.y : fb.x;
                float v = wy0 * (wx0 * va0 + wx1 * va1) + wy1 * (wx0 * vb0 + wx1 * vb1);
                f1.s[j] = f2bf(v);
            }
        }
        __syncthreads();

#pragma unroll
        for (int mt = 0; mt < 4; ++mt) {
            bf16x8 a0 = *(const bf16x8*)&wa[mt * 16 + lane16][quad * 8];
            bf16x8 a1 = *(const bf16x8*)&wa[mt * 16 + lane16][32 + quad * 8];
            acc[mt] = __builtin_amdgcn_mfma_f32_16x16x32_bf16(a0, f0.v, acc[mt], 0, 0, 0);
            acc[mt] = __builtin_amdgcn_mfma_f32_16x16x32_bf16(a1, f1.v, acc[mt], 0, 0, 0);
        }
    }

#pragma unroll
    for (int mt = 0; mt < 4; ++mt) {
#pragma unroll
        for (int r = 0; r < 4; ++r) {
            int o = mt * 16 + quad * 4 + r;
            float v = acc[mt][r] + b_def[g * CG + o];
            out[((size_t)(b * CIN + g * CG + o) * HH + h) * WW + p] = v;
        }
    }
}

extern "C" void kernel_launch(void* const* d_in, const int* in_sizes, int n_in,
                              void* d_out, int out_size, void* d_ws, size_t ws_size,
                              hipStream_t stream) {
    const float* x     = (const float*)d_in[0];
    const float* w_off = (const float*)d_in[1];
    const float* b_off = (const float*)d_in[2];
    const float* w_def = (const float*)d_in[3];
    const float* b_def = (const float*)d_in[4];
    float* out = (float*)d_out;

    char* ws = (char*)d_ws;
    float*          offs = (float*)ws;
    unsigned short* wT   = (unsigned short*)(ws + (size_t)OFFS_ELEMS * 4);
    unsigned short* woT2 = (unsigned short*)(ws + (size_t)OFFS_ELEMS * 4 + (size_t)WT_ELEMS * 2);
    unsigned short* xbf  = (unsigned short*)(ws + XBF_BYTE_OFF);

    int prep_elems = WT_ELEMS + WO2_ELEMS;
    prep_w_kernel<<<(prep_elems + 255) / 256, 256, 0, stream>>>(w_def, w_off, wT, woT2);

    if (ws_size >= NEED_NHWC) {
        prep_x_kernel<<<BATCH * HH, 256, 0, stream>>>(x, xbf);
        conv_off_nhwc<<<BATCH * HH, 256, 0, stream>>>(xbf, woT2, b_off, offs);
        deform_nhwc<<<BATCH * OG * HH, 256, 0, stream>>>(xbf, offs, wT, b_def, out);
    } else {
        conv_off_fb<<<BATCH * HH, 256, 0, stream>>>(x, woT2, b_off, offs);
        deform_fb<<<BATCH * OG * HH, 256, 0, stream>>>(x, offs, wT, b_def, out);
    }
}

// Round 5
// 270.374 us; speedup vs baseline: 3.6330x; 1.0678x over previous
//
#include <hip/hip_runtime.h>
#include <hip/hip_bf16.h>

// Problem constants (B=8, C=256, H=W=64, OG=4, Cg=64, K=9, C_off=72)
#define BATCH 8
#define CIN   256
#define HH    64
#define WW    64
#define HW    4096
#define OG    4
#define CG    64
#define COFF  72

typedef __attribute__((ext_vector_type(8))) short bf16x8;
typedef __attribute__((ext_vector_type(4))) float floatx4;

struct __align__(4) f2 { float x, y; };   // align-4 float2 (fallback path)

static __device__ __forceinline__ short f2bf(float f) {
    unsigned u = __builtin_bit_cast(unsigned, f);
    unsigned r = (u + 0x7FFFu + ((u >> 16) & 1u)) >> 16;   // RNE
    return (short)r;
}
static __device__ __forceinline__ float b2f(unsigned short u) {
    return __builtin_bit_cast(float, ((unsigned)u) << 16);
}

// ws layout:
//   offs  fp32  [B][72][H][W]                       bytes [0, 9437184)
//   wT    bf16  [g][k][o][c]        (4*9*64*64)     bytes [9437184, 9732096)
//   woT2  bf16  [((chunk*9+tap)*80+oc)*32+cc]       bytes [9732096, 10100736)
//   xbf   bf16  [b][y][x][c]  NHWC  (8*4096*256)    bytes [10100736, 26877952)
#define OFFS_ELEMS (BATCH * COFF * HH * WW)      // 2359296
#define WT_ELEMS   (OG * 9 * CG * CG)            // 147456
#define WO2_ELEMS  (8 * 9 * 80 * 32)             // 184320
#define XBF_BYTE_OFF ((size_t)OFFS_ELEMS * 4 + (size_t)WT_ELEMS * 2 + (size_t)WO2_ELEMS * 2)
#define NEED_NHWC (XBF_BYTE_OFF + (size_t)BATCH * HW * CIN * 2)   // 26877952

// ---------------------------------------------------------------------------
// Prep A: transpose weights (both convs) once per call.
// ---------------------------------------------------------------------------
__global__ __launch_bounds__(256) void prep_w_kernel(
    const float* __restrict__ w_def, const float* __restrict__ w_off,
    unsigned short* __restrict__ wT, unsigned short* __restrict__ woT2)
{
    int i = blockIdx.x * 256 + threadIdx.x;
    if (i < WT_ELEMS) {
        int c = i & 63;
        int o = (i >> 6) & 63;
        int gk = i >> 12;          // 0..35
        int k = gk % 9, g = gk / 9;
        float v = w_def[((size_t)((g * CG + o) * CG + c)) * 9 + k];
        wT[i] = (unsigned short)f2bf(v);
    } else if (i < WT_ELEMS + WO2_ELEMS) {
        int j = i - WT_ELEMS;
        int cc = j & 31;
        int oc = (j >> 5) % 80;
        int ct = (j >> 5) / 80;    // chunk*9 + tap
        int tap = ct % 9, chunk = ct / 9;
        float v = 0.f;
        if (oc < COFF)
            v = w_off[((size_t)(oc * CIN + chunk * 32 + cc)) * 9 + tap];
        woT2[j] = (unsigned short)f2bf(v);
    }
}

// ---------------------------------------------------------------------------
// Prep B: x NCHW fp32 -> NHWC bf16.  grid = B*H blocks, one (b,y) row each.
// ---------------------------------------------------------------------------
__global__ __launch_bounds__(256) void prep_x_kernel(
    const float* __restrict__ x, unsigned short* __restrict__ xbf)
{
    const int b = blockIdx.x >> 6;
    const int y = blockIdx.x & 63;
    const int t = threadIdx.x;

    __shared__ short tile[64][258];   // [px][c], pad 258 keeps b16 writes 2-way

#pragma unroll
    for (int it = 0; it < 16; ++it) {
        int i  = t + it * 256;        // i < 4096
        int c  = i >> 4;
        int p4 = (i & 15) << 2;
        float4 v = *(const float4*)(x + (((size_t)(b * CIN + c)) << 12) + (y << 6) + p4);
        tile[p4 + 0][c] = f2bf(v.x);
        tile[p4 + 1][c] = f2bf(v.y);
        tile[p4 + 2][c] = f2bf(v.z);
        tile[p4 + 3][c] = f2bf(v.w);
    }
    __syncthreads();

    unsigned short* dst = xbf + (((size_t)(b * HW)) << 8) + ((size_t)(y * WW) << 8);
#pragma unroll
    for (int k = 0; k < 8; ++k) {
        int i  = t + k * 256;         // i < 2048
        int p  = i >> 5;
        int c8 = (i & 31) << 3;
        const unsigned* tp = (const unsigned*)&tile[p][c8];
        uint4 r = make_uint4(tp[0], tp[1], tp[2], tp[3]);
        *(uint4*)(dst + ((size_t)p << 8) + c8) = r;
    }
}

// ---------------------------------------------------------------------------
// Kernel 1 (NHWC): offsets = conv3x3(x) + b_off. Implicit-GEMM bf16 MFMA.
// grid = B*H, 256 threads = 4 waves. B row-tile staged in LDS per chunk
// (coalesced NHWC sweeps, halo pre-zeroed once); B-frag = 1 ds_read_b128.
// A-frags from global woT2 (L2-hot), fully unrolled per chunk.
// ---------------------------------------------------------------------------
__global__ __launch_bounds__(256) void conv_off_nhwc(
    const unsigned short* __restrict__ xbf, const unsigned short* __restrict__ woT2,
    const float* __restrict__ b_off, float* __restrict__ offs)
{
    const int b = blockIdx.x >> 6;
    const int h = blockIdx.x & 63;
    const int t = threadIdx.x;
    const int wv = t >> 6;
    const int l  = t & 63;
    const int lane16 = l & 15;
    const int quad   = l >> 4;
    const int p = wv * 16 + lane16;

    __shared__ short xs[3][66][48];   // [ky][record][cc] stride 48: aligned, <=4-way

    floatx4 acc[5];
#pragma unroll
    for (int mt = 0; mt < 5; ++mt) acc[mt] = (floatx4){0.f, 0.f, 0.f, 0.f};

    // zero halo records (records 0 and 65 of each row) once
    if (t < 24) {
        int row = t >> 3;               // 0..2
        int rec = (t & 4) ? 65 : 0;
        int sub = t & 3;
        *(uint4*)&xs[row][rec][sub * 8] = make_uint4(0, 0, 0, 0);
    }

    const int r   = t >> 2;   // record 0..63
    const int sub = t & 3;    // 16B sub-chunk

    for (int chunk = 0; chunk < 8; ++chunk) {
        __syncthreads();
        // stage 3 rows x 64 records x 64B (this chunk's 32 channels)
#pragma unroll
        for (int ky = 0; ky < 3; ++ky) {
            int yy = h + ky - 1;
            uint4 v = make_uint4(0, 0, 0, 0);
            if ((unsigned)yy < 64u)
                v = *(const uint4*)(xbf + (((size_t)(b * HW + (yy << 6) + r)) << 8)
                                        + chunk * 32 + sub * 8);
            *(uint4*)&xs[ky][r + 1][sub * 8] = v;
        }
        __syncthreads();

#pragma unroll
        for (int tap = 0; tap < 9; ++tap) {
            const int ky = tap / 3, kx = tap % 3;
            bf16x8 bfrag = *(const bf16x8*)&xs[ky][p + kx][quad * 8];
            const unsigned short* abase =
                woT2 + ((size_t)(chunk * 9 + tap) * 80) * 32 + quad * 8;
#pragma unroll
            for (int mt = 0; mt < 5; ++mt) {
                bf16x8 afrag = *(const bf16x8*)(abase + (mt * 16 + lane16) * 32);
                acc[mt] = __builtin_amdgcn_mfma_f32_16x16x32_bf16(afrag, bfrag, acc[mt], 0, 0, 0);
            }
        }
    }

#pragma unroll
    for (int mt = 0; mt < 5; ++mt) {
#pragma unroll
        for (int rg = 0; rg < 4; ++rg) {
            int oc = mt * 16 + quad * 4 + rg;
            if (oc < COFF)
                offs[((size_t)(b * COFF + oc) << 12) + (h << 6) + p] =
                    acc[mt][rg] + b_off[oc];
        }
    }
}

// ---------------------------------------------------------------------------
// Kernel 2 (NHWC): deformable conv via bf16 MFMA. NO LDS, NO barriers.
// Explicit 2-slot software pipeline over taps: params+gathers for tap k+1
// issue before blending tap k, doubling in-flight memory parallelism.
// ---------------------------------------------------------------------------
union bfr { bf16x8 v; unsigned short s[8]; };

__global__ __launch_bounds__(256) void deform_nhwc(
    const unsigned short* __restrict__ xbf, const float* __restrict__ offs,
    const unsigned short* __restrict__ wT, const float* __restrict__ b_def,
    float* __restrict__ out)
{
    const int h  = blockIdx.x & 63;
    const int bg = blockIdx.x >> 6;
    const int g  = bg & 3;
    const int b  = bg >> 2;
    const int t  = threadIdx.x;
    const int wv = t >> 6;
    const int l  = t & 63;
    const int lane16 = l & 15;
    const int quad   = l >> 4;
    const int p = wv * 16 + lane16;

    floatx4 acc[4];
#pragma unroll
    for (int mt = 0; mt < 4; ++mt) acc[mt] = (floatx4){0.f, 0.f, 0.f, 0.f};

    // prefetch all 18 offset values for this pixel
    float dyv[9], dxv[9];
    {
        const float* ofb = offs + (((size_t)(b * COFF + g * 18)) * HH + h) * WW + p;
#pragma unroll
        for (int k = 0; k < 9; ++k) {
            dyv[k] = ofb[(size_t)(2 * k) * HW];
            dxv[k] = ofb[(size_t)(2 * k + 1) * HW];
        }
    }

    const unsigned short* xb = xbf + (((size_t)(b * HW)) << 8) + g * 64;

    int   cidx[2][4];
    float cwgt[2][4];
    bfr   gl[2][4], gh[2][4];

    auto params = [&](int k, int s) {
        float py = dyv[k] + (float)(h + (k / 3) - 1);
        float px = dxv[k] + (float)(p + (k % 3) - 1);
        float y0f = floorf(py), x0f = floorf(px);
        float fy = py - y0f, fx = px - x0f;
        int y0 = (int)y0f, x0 = (int)x0f;
        float wy0 = ((y0 >= 0) & (y0 < HH)) ? (1.f - fy) : 0.f;
        float wy1 = ((y0 >= -1) & (y0 < HH - 1)) ? fy : 0.f;
        float wx0 = ((x0 >= 0) & (x0 < WW)) ? (1.f - fx) : 0.f;
        float wx1 = ((x0 >= -1) & (x0 < WW - 1)) ? fx : 0.f;
        cwgt[s][0] = wy0 * wx0; cwgt[s][1] = wy0 * wx1;
        cwgt[s][2] = wy1 * wx0; cwgt[s][3] = wy1 * wx1;
        int yia = min(max(y0, 0), HH - 1), yib = min(max(y0 + 1, 0), HH - 1);
        int xia = min(max(x0, 0), WW - 1), xib = min(max(x0 + 1, 0), WW - 1);
        cidx[s][0] = ((yia << 6) + xia) << 8;
        cidx[s][1] = ((yia << 6) + xib) << 8;
        cidx[s][2] = ((yib << 6) + xia) << 8;
        cidx[s][3] = ((yib << 6) + xib) << 8;
    };
    auto gather = [&](int s) {
        const int co = quad * 8;
#pragma unroll
        for (int c = 0; c < 4; ++c) {
            gl[s][c].v = *(const bf16x8*)(xb + cidx[s][c] + co);
            gh[s][c].v = *(const bf16x8*)(xb + cidx[s][c] + co + 32);
        }
    };

    params(0, 0);
    gather(0);

#pragma unroll
    for (int k = 0; k < 9; ++k) {
        const int s = k & 1, s2 = s ^ 1;
        if (k < 8) { params(k + 1, s2); gather(s2); }

        // ---- blend slot s ----
        float w0 = cwgt[s][0], w1 = cwgt[s][1], w2 = cwgt[s][2], w3 = cwgt[s][3];
        bfr f0, f1;
#pragma unroll
        for (int j = 0; j < 8; ++j) {
            float v0 = w0 * b2f(gl[s][0].s[j]) + w1 * b2f(gl[s][1].s[j])
                     + w2 * b2f(gl[s][2].s[j]) + w3 * b2f(gl[s][3].s[j]);
            float v1 = w0 * b2f(gh[s][0].s[j]) + w1 * b2f(gh[s][1].s[j])
                     + w2 * b2f(gh[s][2].s[j]) + w3 * b2f(gh[s][3].s[j]);
            f0.s[j] = (unsigned short)f2bf(v0);
            f1.s[j] = (unsigned short)f2bf(v1);
        }

        // ---- A-frags from global wT + MFMA ----
        const int co = quad * 8;
        const unsigned short* wk = wT + (((size_t)(g * 9 + k)) << 12);
#pragma unroll
        for (int mt = 0; mt < 4; ++mt) {
            bf16x8 a0 = *(const bf16x8*)(wk + (mt * 16 + lane16) * 64 + co);
            bf16x8 a1 = *(const bf16x8*)(wk + (mt * 16 + lane16) * 64 + 32 + co);
            acc[mt] = __builtin_amdgcn_mfma_f32_16x16x32_bf16(a0, f0.v, acc[mt], 0, 0, 0);
            acc[mt] = __builtin_amdgcn_mfma_f32_16x16x32_bf16(a1, f1.v, acc[mt], 0, 0, 0);
        }
    }

#pragma unroll
    for (int mt = 0; mt < 4; ++mt) {
#pragma unroll
        for (int rg = 0; rg < 4; ++rg) {
            int o = mt * 16 + quad * 4 + rg;
            float v = acc[mt][rg] + b_def[g * CG + o];
            out[((size_t)(b * CIN + g * CG + o) * HH + h) * WW + p] = v;
        }
    }
}

// ===========================================================================
// FALLBACK PATH (ws too small for xbf): round-3 kernels, unchanged.
// ===========================================================================
__global__ __launch_bounds__(256) void conv_off_fb(
    const float* __restrict__ x, const unsigned short* __restrict__ woT2,
    const float* __restrict__ b_off, float* __restrict__ offs)
{
    const int b = blockIdx.x >> 6;
    const int h = blockIdx.x & 63;
    const int t = threadIdx.x;
    const int wv = t >> 6;
    const int l  = t & 63;
    const int lane16 = l & 15;
    const int quad   = l >> 4;
    const int p = wv * 16 + lane16;

    __shared__ short xs[3][66][40];

    floatx4 acc[5];
#pragma unroll
    for (int mt = 0; mt < 5; ++mt) acc[mt] = (floatx4){0.f, 0.f, 0.f, 0.f};

    for (int chunk = 0; chunk < 8; ++chunk) {
        __syncthreads();
        for (int i = t; i < 3 * 66 * 32; i += 256) {
            int wp  = i % 66;
            int rem = i / 66;
            int cc  = rem & 31;
            int ky  = rem >> 5;
            int yy = h + ky - 1;
            int xx = wp - 1;
            float v = 0.f;
            if (yy >= 0 && yy < HH && xx >= 0 && xx < WW)
                v = x[((size_t)(b * CIN + chunk * 32 + cc) << 12) + (yy << 6) + xx];
            xs[ky][wp][cc] = f2bf(v);
        }
        __syncthreads();

#pragma unroll
        for (int tap = 0; tap < 9; ++tap) {
            const int ky = tap / 3, kx = tap % 3;
            bf16x8 bfrag = *(const bf16x8*)&xs[ky][p + kx][quad * 8];
            const unsigned short* abase =
                woT2 + ((size_t)(chunk * 9 + tap) * 80) * 32 + quad * 8;
#pragma unroll
            for (int mt = 0; mt < 5; ++mt) {
                bf16x8 afrag = *(const bf16x8*)(abase + (mt * 16 + lane16) * 32);
                acc[mt] = __builtin_amdgcn_mfma_f32_16x16x32_bf16(afrag, bfrag, acc[mt], 0, 0, 0);
            }
        }
    }

#pragma unroll
    for (int mt = 0; mt < 5; ++mt) {
#pragma unroll
        for (int rg = 0; rg < 4; ++rg) {
            int oc = mt * 16 + quad * 4 + rg;
            if (oc < COFF)
                offs[((size_t)(b * COFF + oc) << 12) + (h << 6) + p] =
                    acc[mt][rg] + b_off[oc];
        }
    }
}

__global__ __launch_bounds__(256) void deform_fb(
    const float* __restrict__ x, const float* __restrict__ offs,
    const unsigned short* __restrict__ wT, const float* __restrict__ b_def,
    float* __restrict__ out)
{
    const int h  = blockIdx.x & 63;
    const int bg = blockIdx.x >> 6;
    const int g  = bg & 3;
    const int b  = bg >> 2;
    const int t  = threadIdx.x;
    const int wv = t >> 6;
    const int l  = t & 63;
    const int lane16 = l & 15;
    const int quad   = l >> 4;
    const int p = wv * 16 + lane16;

    __shared__ short wa[CG][72];

    floatx4 acc[4];
#pragma unroll
    for (int mt = 0; mt < 4; ++mt) acc[mt] = (floatx4){0.f, 0.f, 0.f, 0.f};

    const float* xg = x + (size_t)(b * CIN + g * CG) * HW;

    float dyv[9], dxv[9];
    {
        const float* ofb = offs + (((size_t)(b * COFF + g * 18)) * HH + h) * WW + p;
#pragma unroll
        for (int k = 0; k < 9; ++k) {
            dyv[k] = ofb[(size_t)(2 * k) * HW];
            dxv[k] = ofb[(size_t)(2 * k + 1) * HW];
        }
    }

    for (int k = 0; k < 9; ++k) {
        __syncthreads();
        {
            const uint4* src = (const uint4*)(wT + ((size_t)(g * 9 + k) << 12)) + t * 2;
            uint4 d0 = src[0], d1 = src[1];
            int o = t >> 2, cc = (t & 3) << 4;
            uint4* dst = (uint4*)&wa[o][cc];
            dst[0] = d0; dst[1] = d1;
        }
        float py = dyv[k] + (float)(h + (k / 3) - 1);
        float px = dxv[k] + (float)(p + (k % 3) - 1);
        float y0f = floorf(py), x0f = floorf(px);
        float fy = py - y0f, fx = px - x0f;
        int y0 = (int)y0f, x0 = (int)x0f;
        float wy0 = ((y0 >= 0) & (y0 < HH)) ? (1.f - fy) : 0.f;
        float wy1 = ((y0 >= -1) & (y0 < HH - 1)) ? fy : 0.f;
        float wx0 = ((x0 >= 0) & (x0 < WW)) ? (1.f - fx) : 0.f;
        float wx1 = ((x0 >= -1) & (x0 < WW - 1)) ? fx : 0.f;
        int yia = min(max(y0, 0), HH - 1);
        int yib = min(max(y0 + 1, 0), HH - 1);
        int xia = min(max(x0, 0), WW - 1);
        int xib = min(max(x0 + 1, 0), WW - 1);
        int xbase = min(xia, WW - 2);
        bool sa = (xia != xbase);
        bool sb = (xib != xbase);
        int ra = yia * WW + xbase;
        int rb = yib * WW + xbase;

        union { bf16x8 v; short s[8]; } f0, f1;
#pragma unroll
        for (int j = 0; j < 8; ++j) {
            int c = quad * 8 + j;
            {
                const float* xc = xg + (size_t)c * HW;
                f2 fa = *(const f2*)(xc + ra);
                f2 fb = *(const f2*)(xc + rb);
                float va0 = sa ? fa.y : fa.x;
                float va1 = sb ? fa.y : fa.x;
                float vb0 = sa ? fb.y : fb.x;
                float vb1 = sb ? fb.y : fb.x;
                float v = wy0 * (wx0 * va0 + wx1 * va1) + wy1 * (wx0 * vb0 + wx1 * vb1);
                f0.s[j] = f2bf(v);
            }
            {
                const float* xc = xg + (size_t)(c + 32) * HW;
                f2 fa = *(const f2*)(xc + ra);
                f2 fb = *(const f2*)(xc + rb);
                float va0 = sa ? fa.y : fa.x;
                float va1 = sb ? fa.y : fa.x;
                float vb0 = sa ? fb.y : fb.x;
                float vb1 = sb ? fb.y : fb.x;
                float v = wy0 * (wx0 * va0 + wx1 * va1) + wy1 * (wx0 * vb0 + wx1 * vb1);
                f1.s[j] = f2bf(v);
            }
        }
        __syncthreads();

#pragma unroll
        for (int mt = 0; mt < 4; ++mt) {
            bf16x8 a0 = *(const bf16x8*)&wa[mt * 16 + lane16][quad * 8];
            bf16x8 a1 = *(const bf16x8*)&wa[mt * 16 + lane16][32 + quad * 8];
            acc[mt] = __builtin_amdgcn_mfma_f32_16x16x32_bf16(a0, f0.v, acc[mt], 0, 0, 0);
            acc[mt] = __builtin_amdgcn_mfma_f32_16x16x32_bf16(a1, f1.v, acc[mt], 0, 0, 0);
        }
    }

#pragma unroll
    for (int mt = 0; mt < 4; ++mt) {
#pragma unroll
        for (int rg = 0; rg < 4; ++rg) {
            int o = mt * 16 + quad * 4 + rg;
            float v = acc[mt][rg] + b_def[g * CG + o];
            out[((size_t)(b * CIN + g * CG + o) * HH + h) * WW + p] = v;
        }
    }
}

extern "C" void kernel_launch(void* const* d_in, const int* in_sizes, int n_in,
                              void* d_out, int out_size, void* d_ws, size_t ws_size,
                              hipStream_t stream) {
    const float* x     = (const float*)d_in[0];
    const float* w_off = (const float*)d_in[1];
    const float* b_off = (const float*)d_in[2];
    const float* w_def = (const float*)d_in[3];
    const float* b_def = (const float*)d_in[4];
    float* out = (float*)d_out;

    char* ws = (char*)d_ws;
    float*          offs = (float*)ws;
    unsigned short* wT   = (unsigned short*)(ws + (size_t)OFFS_ELEMS * 4);
    unsigned short* woT2 = (unsigned short*)(ws + (size_t)OFFS_ELEMS * 4 + (size_t)WT_ELEMS * 2);
    unsigned short* xbf  = (unsigned short*)(ws + XBF_BYTE_OFF);

    int prep_elems = WT_ELEMS + WO2_ELEMS;
    prep_w_kernel<<<(prep_elems + 255) / 256, 256, 0, stream>>>(w_def, w_off, wT, woT2);

    if (ws_size >= NEED_NHWC) {
        prep_x_kernel<<<BATCH * HH, 256, 0, stream>>>(x, xbf);
        conv_off_nhwc<<<BATCH * HH, 256, 0, stream>>>(xbf, woT2, b_off, offs);
        deform_nhwc<<<BATCH * OG * HH, 256, 0, stream>>>(xbf, offs, wT, b_def, out);
    } else {
        conv_off_fb<<<BATCH * HH, 256, 0, stream>>>(x, woT2, b_off, offs);
        deform_fb<<<BATCH * OG * HH, 256, 0, stream>>>(x, offs, wT, b_def, out);
    }
}

// Round 6
// 247.676 us; speedup vs baseline: 3.9660x; 1.0916x over previous
//
#include <hip/hip_runtime.h>
#include <hip/hip_bf16.h>

// Problem constants (B=8, C=256, H=W=64, OG=4, Cg=64, K=9, C_off=72)
#define BATCH 8
#define CIN   256
#define HH    64
#define WW    64
#define HW    4096
#define OG    4
#define CG    64
#define COFF  72

typedef __attribute__((ext_vector_type(8))) short bf16x8;
typedef __attribute__((ext_vector_type(4))) float floatx4;

struct __align__(4) f2 { float x, y; };   // align-4 float2 (fallback path)

static __device__ __forceinline__ short f2bf(float f) {
    unsigned u = __builtin_bit_cast(unsigned, f);
    unsigned r = (u + 0x7FFFu + ((u >> 16) & 1u)) >> 16;   // RNE
    return (short)r;
}
static __device__ __forceinline__ float b2f(unsigned short u) {
    return __builtin_bit_cast(float, ((unsigned)u) << 16);
}

// ws layout:
//   offs  fp32  [B][72][H][W]                       bytes [0, 9437184)
//   wT3   bf16  fragment-order deform weights       bytes [9437184, 9732096)
//   woT3  bf16  fragment-order offset-conv weights  bytes [9732096, 10100736)
//   xbf   bf16  [b][y][x][c]  NHWC  (8*4096*256)    bytes [10100736, 26877952)
#define OFFS_ELEMS (BATCH * COFF * HH * WW)      // 2359296
#define WT_ELEMS   (OG * 9 * 4 * 2 * 64 * 8)     // 147456
#define WO3_ELEMS  (8 * 9 * 5 * 64 * 8)          // 184320
#define XBF_BYTE_OFF ((size_t)OFFS_ELEMS * 4 + (size_t)WT_ELEMS * 2 + (size_t)WO3_ELEMS * 2)
#define NEED_NHWC (XBF_BYTE_OFF + (size_t)BATCH * HW * CIN * 2)   // 26877952

// ---------------------------------------------------------------------------
// Prep A: weights -> MFMA-fragment order (lane-major => coalesced A loads).
//   wT3 [((((g*9+k)*4+mt)*2+kh)*64 + l)*8 + j] = bf16(w_def[o=mt*16+(l&15)][c=kh*32+(l>>4)*8+j] @tap k, group g)
//   woT3[(((chunk*9+tap)*5+mt)*64 + l)*8 + j]  = bf16(w_off[o=mt*16+(l&15)][c=chunk*32+(l>>4)*8+j] @tap]), 0 if o>=72
// ---------------------------------------------------------------------------
__global__ __launch_bounds__(256) void prep_w_kernel(
    const float* __restrict__ w_def, const float* __restrict__ w_off,
    unsigned short* __restrict__ wT3, unsigned short* __restrict__ woT3)
{
    int i = blockIdx.x * 256 + threadIdx.x;
    if (i < WT_ELEMS) {
        int j = i & 7;
        int l = (i >> 3) & 63;
        int rest = i >> 9;        // ((g*9+k)*4+mt)*2+kh
        int kh = rest & 1;
        int mt = (rest >> 1) & 3;
        int gk = rest >> 3;       // g*9+k
        int k = gk % 9, g = gk / 9;
        int o = mt * 16 + (l & 15);
        int c = kh * 32 + (l >> 4) * 8 + j;
        wT3[i] = (unsigned short)f2bf(
            w_def[((size_t)((g * CG + o) * CG + c)) * 9 + k]);
    } else if (i < WT_ELEMS + WO3_ELEMS) {
        int idx = i - WT_ELEMS;
        int j = idx & 7;
        int l = (idx >> 3) & 63;
        int rest = idx >> 9;      // (chunk*9+tap)*5 + mt
        int mt = rest % 5;
        int ct = rest / 5;
        int tap = ct % 9, chunk = ct / 9;
        int o = mt * 16 + (l & 15);
        int c = chunk * 32 + (l >> 4) * 8 + j;
        float v = (o < COFF) ? w_off[((size_t)(o * CIN + c)) * 9 + tap] : 0.f;
        woT3[idx] = (unsigned short)f2bf(v);
    }
}

// ---------------------------------------------------------------------------
// Prep B: x NCHW fp32 -> NHWC bf16.  grid = B*H blocks, one (b,y) row each.
// ---------------------------------------------------------------------------
__global__ __launch_bounds__(256) void prep_x_kernel(
    const float* __restrict__ x, unsigned short* __restrict__ xbf)
{
    const int b = blockIdx.x >> 6;
    const int y = blockIdx.x & 63;
    const int t = threadIdx.x;

    __shared__ short tile[64][258];   // [px][c], pad 258 keeps b16 writes 2-way

#pragma unroll
    for (int it = 0; it < 16; ++it) {
        int i  = t + it * 256;        // i < 4096
        int c  = i >> 4;
        int p4 = (i & 15) << 2;
        float4 v = *(const float4*)(x + (((size_t)(b * CIN + c)) << 12) + (y << 6) + p4);
        tile[p4 + 0][c] = f2bf(v.x);
        tile[p4 + 1][c] = f2bf(v.y);
        tile[p4 + 2][c] = f2bf(v.z);
        tile[p4 + 3][c] = f2bf(v.w);
    }
    __syncthreads();

    unsigned short* dst = xbf + (((size_t)(b * HW)) << 8) + ((size_t)(y * WW) << 8);
#pragma unroll
    for (int k = 0; k < 8; ++k) {
        int i  = t + k * 256;         // i < 2048
        int p  = i >> 5;
        int c8 = (i & 31) << 3;
        const unsigned* tp = (const unsigned*)&tile[p][c8];
        uint4 r = make_uint4(tp[0], tp[1], tp[2], tp[3]);
        *(uint4*)(dst + ((size_t)p << 8) + c8) = r;
    }
}

// ---------------------------------------------------------------------------
// Kernel 1 (NHWC): offsets = conv3x3(x) + b_off. Implicit-GEMM bf16 MFMA.
// 512 threads = 8 waves: waves 0-3 do M-tiles {0,1,2}, waves 4-7 do {3,4}
// for the same pixels -> 16 waves/CU. B row-tile staged in LDS per chunk;
// A-frags are COALESCED loads from fragment-order woT3 (lane l -> l*16B).
// ---------------------------------------------------------------------------
__global__ __launch_bounds__(512) void conv_off_nhwc(
    const unsigned short* __restrict__ xbf, const unsigned short* __restrict__ woT3,
    const float* __restrict__ b_off, float* __restrict__ offs)
{
    const int b = blockIdx.x >> 6;
    const int h = blockIdx.x & 63;
    const int t = threadIdx.x;
    const int wv = t >> 6;
    const int l  = t & 63;
    const int lane16 = l & 15;
    const int quad   = l >> 4;
    const int pg = wv & 3;
    const int mh = wv >> 2;
    const int p  = pg * 16 + lane16;
    const int mt0 = mh ? 3 : 0;
    const int nmt = mh ? 2 : 3;

    __shared__ short xs[3][66][48];   // [ky][record][cc] stride 48: aligned, <=4-way

    floatx4 acc[3];
#pragma unroll
    for (int m = 0; m < 3; ++m) acc[m] = (floatx4){0.f, 0.f, 0.f, 0.f};

    // zero halo records (records 0 and 65 of each row) once
    if (t < 24) {
        int row = t >> 3;               // 0..2
        int rec = (t & 4) ? 65 : 0;
        int sub = t & 3;
        *(uint4*)&xs[row][rec][sub * 8] = make_uint4(0, 0, 0, 0);
    }

    for (int chunk = 0; chunk < 8; ++chunk) {
        __syncthreads();
        // stage 3 rows x 64 records x 64B (this chunk's 32 channels); 768 uint4
        for (int s = t; s < 768; s += 512) {
            int sub = s & 3;
            int rec = (s >> 2) & 63;
            int ky  = s >> 8;
            int yy = h + ky - 1;
            uint4 v = make_uint4(0, 0, 0, 0);
            if ((unsigned)yy < 64u)
                v = *(const uint4*)(xbf + (((size_t)(b * HW + (yy << 6) + rec)) << 8)
                                        + chunk * 32 + sub * 8);
            *(uint4*)&xs[ky][rec + 1][sub * 8] = v;
        }
        __syncthreads();

#pragma unroll
        for (int tap = 0; tap < 9; ++tap) {
            const int ky = tap / 3, kx = tap % 3;
            bf16x8 bfrag = *(const bf16x8*)&xs[ky][p + kx][quad * 8];
            const unsigned short* ab =
                woT3 + ((size_t)((chunk * 9 + tap) * 5 + mt0)) * 512 + l * 8;
            for (int m = 0; m < nmt; ++m) {
                bf16x8 afrag = *(const bf16x8*)(ab + m * 512);
                acc[m] = __builtin_amdgcn_mfma_f32_16x16x32_bf16(afrag, bfrag, acc[m], 0, 0, 0);
            }
        }
    }

    for (int m = 0; m < nmt; ++m) {
#pragma unroll
        for (int rg = 0; rg < 4; ++rg) {
            int oc = (mt0 + m) * 16 + quad * 4 + rg;
            if (oc < COFF)
                offs[((size_t)(b * COFF + oc) << 12) + (h << 6) + p] =
                    acc[m][rg] + b_off[oc];
        }
    }
}

// ---------------------------------------------------------------------------
// Kernel 2 (NHWC): deformable conv via bf16 MFMA. NO LDS, NO barriers.
// A-frags are COALESCED loads from fragment-order wT3 (lane l -> l*16B);
// only the 8 bilinear corner gathers per tap remain scattered.
// ---------------------------------------------------------------------------
union bfr { bf16x8 v; unsigned short s[8]; };

__global__ __launch_bounds__(256) void deform_nhwc(
    const unsigned short* __restrict__ xbf, const float* __restrict__ offs,
    const unsigned short* __restrict__ wT3, const float* __restrict__ b_def,
    float* __restrict__ out)
{
    const int h  = blockIdx.x & 63;
    const int bg = blockIdx.x >> 6;
    const int g  = bg & 3;
    const int b  = bg >> 2;
    const int t  = threadIdx.x;
    const int wv = t >> 6;
    const int l  = t & 63;
    const int lane16 = l & 15;
    const int quad   = l >> 4;
    const int p = wv * 16 + lane16;

    floatx4 acc[4];
#pragma unroll
    for (int mt = 0; mt < 4; ++mt) acc[mt] = (floatx4){0.f, 0.f, 0.f, 0.f};

    // prefetch all 18 offset values for this pixel
    float dyv[9], dxv[9];
    {
        const float* ofb = offs + (((size_t)(b * COFF + g * 18)) * HH + h) * WW + p;
#pragma unroll
        for (int k = 0; k < 9; ++k) {
            dyv[k] = ofb[(size_t)(2 * k) * HW];
            dxv[k] = ofb[(size_t)(2 * k + 1) * HW];
        }
    }

    const unsigned short* xb = xbf + (((size_t)(b * HW)) << 8) + g * 64;

#pragma unroll
    for (int k = 0; k < 9; ++k) {
        // ---- bilinear params ----
        float py = dyv[k] + (float)(h + (k / 3) - 1);
        float px = dxv[k] + (float)(p + (k % 3) - 1);
        float y0f = floorf(py), x0f = floorf(px);
        float fy = py - y0f, fx = px - x0f;
        int y0 = (int)y0f, x0 = (int)x0f;
        float wy0 = ((y0 >= 0) & (y0 < HH)) ? (1.f - fy) : 0.f;
        float wy1 = ((y0 >= -1) & (y0 < HH - 1)) ? fy : 0.f;
        float wx0 = ((x0 >= 0) & (x0 < WW)) ? (1.f - fx) : 0.f;
        float wx1 = ((x0 >= -1) & (x0 < WW - 1)) ? fx : 0.f;
        float w0 = wy0 * wx0, w1 = wy0 * wx1, w2 = wy1 * wx0, w3 = wy1 * wx1;
        int yia = min(max(y0, 0), HH - 1), yib = min(max(y0 + 1, 0), HH - 1);
        int xia = min(max(x0, 0), WW - 1), xib = min(max(x0 + 1, 0), WW - 1);
        int i0 = ((yia << 6) + xia) << 8;
        int i1 = ((yia << 6) + xib) << 8;
        int i2 = ((yib << 6) + xia) << 8;
        int i3 = ((yib << 6) + xib) << 8;

        // ---- gather: 4 corners x 2 channel-halves, 16B each (scattered) ----
        const int co = quad * 8;
        bfr g0L, g1L, g2L, g3L, g0H, g1H, g2H, g3H;
        g0L.v = *(const bf16x8*)(xb + i0 + co);
        g1L.v = *(const bf16x8*)(xb + i1 + co);
        g2L.v = *(const bf16x8*)(xb + i2 + co);
        g3L.v = *(const bf16x8*)(xb + i3 + co);
        g0H.v = *(const bf16x8*)(xb + i0 + co + 32);
        g1H.v = *(const bf16x8*)(xb + i1 + co + 32);
        g2H.v = *(const bf16x8*)(xb + i2 + co + 32);
        g3H.v = *(const bf16x8*)(xb + i3 + co + 32);

        bfr f0, f1;
#pragma unroll
        for (int j = 0; j < 8; ++j) {
            float v0 = w0 * b2f(g0L.s[j]) + w1 * b2f(g1L.s[j])
                     + w2 * b2f(g2L.s[j]) + w3 * b2f(g3L.s[j]);
            float v1 = w0 * b2f(g0H.s[j]) + w1 * b2f(g1H.s[j])
                     + w2 * b2f(g2H.s[j]) + w3 * b2f(g3H.s[j]);
            f0.s[j] = (unsigned short)f2bf(v0);
            f1.s[j] = (unsigned short)f2bf(v1);
        }

        // ---- A-frags: coalesced from fragment-order wT3 + MFMA ----
        const unsigned short* wk = wT3 + ((size_t)(g * 9 + k) << 12) + l * 8;
#pragma unroll
        for (int mt = 0; mt < 4; ++mt) {
            bf16x8 a0 = *(const bf16x8*)(wk + (mt * 2 + 0) * 512);
            bf16x8 a1 = *(const bf16x8*)(wk + (mt * 2 + 1) * 512);
            acc[mt] = __builtin_amdgcn_mfma_f32_16x16x32_bf16(a0, f0.v, acc[mt], 0, 0, 0);
            acc[mt] = __builtin_amdgcn_mfma_f32_16x16x32_bf16(a1, f1.v, acc[mt], 0, 0, 0);
        }
    }

#pragma unroll
    for (int mt = 0; mt < 4; ++mt) {
#pragma unroll
        for (int rg = 0; rg < 4; ++rg) {
            int o = mt * 16 + quad * 4 + rg;
            float v = acc[mt][rg] + b_def[g * CG + o];
            out[((size_t)(b * CIN + g * CG + o) * HH + h) * WW + p] = v;
        }
    }
}

// ===========================================================================
// FALLBACK PATH (ws too small for xbf): fp32, correctness-first (never taken
// on this harness -- ws has been >= 26.9MB in all rounds).
// ===========================================================================
__global__ __launch_bounds__(256) void conv_off_fb(
    const float* __restrict__ x, const float* __restrict__ w_off,
    const float* __restrict__ b_off, float* __restrict__ offs)
{
    const int b = blockIdx.x >> 6;
    const int h = blockIdx.x & 63;
    const int t = threadIdx.x;
    const int w = t & 63;
    const int q = t >> 6;

    __shared__ float xsf[3][8][WW + 2];
    __shared__ float wtf[9][8][COFF];

    float acc[18];
#pragma unroll
    for (int j = 0; j < 18; ++j) acc[j] = 0.f;

    for (int c0 = 0; c0 < CIN; c0 += 8) {
        __syncthreads();
        for (int i = t; i < 3 * 8 * (WW + 2); i += 256) {
            int wp = i % (WW + 2);
            int rem = i / (WW + 2);
            int cc = rem % 8;
            int ky = rem / 8;
            int yy = h + ky - 1;
            int xx = wp - 1;
            float v = 0.f;
            if (yy >= 0 && yy < HH && xx >= 0 && xx < WW)
                v = x[(((size_t)b * CIN + c0 + cc) * HH + yy) * WW + xx];
            xsf[ky][cc][wp] = v;
        }
        for (int i = t; i < 9 * 8 * COFF; i += 256) {
            int oc = i % COFF;
            int rem = i / COFF;
            int cc = rem % 8;
            int tap = rem / 8;
            wtf[tap][cc][oc] = w_off[((size_t)oc * CIN + c0 + cc) * 9 + tap];
        }
        __syncthreads();
        for (int tap = 0; tap < 9; ++tap) {
            const int ky = tap / 3, kx = tap % 3;
#pragma unroll
            for (int cc = 0; cc < 8; ++cc) {
                float xv = xsf[ky][cc][w + kx];
#pragma unroll
                for (int j = 0; j < 18; ++j)
                    acc[j] += xv * wtf[tap][cc][q * 18 + j];
            }
        }
    }
#pragma unroll
    for (int j = 0; j < 18; ++j) {
        int oc = q * 18 + j;
        offs[(((size_t)b * COFF + oc) * HH + h) * WW + w] = acc[j] + b_off[oc];
    }
}

__global__ __launch_bounds__(256) void deform_fb(
    const float* __restrict__ x, const float* __restrict__ offs,
    const float* __restrict__ w_def, const float* __restrict__ b_def,
    float* __restrict__ out)
{
    const int h  = blockIdx.x & 63;
    const int bg = blockIdx.x >> 6;
    const int g  = bg & 3;
    const int b  = bg >> 2;
    const int t  = threadIdx.x;
    const int w  = t & 63;
    const int q  = t >> 6;

    __shared__ float vlds[CG][WW];
    __shared__ float wt2[CG][CG];
    __shared__ int   sidx[4][WW];
    __shared__ float swgt[4][WW];

    float acc[16];
#pragma unroll
    for (int j = 0; j < 16; ++j) acc[j] = 0.f;

    const float* xg = x + ((size_t)(b * CIN + g * CG)) * HW;

    for (int k = 0; k < 9; ++k) {
        __syncthreads();
        if (t < 64) {
            const int ky = k / 3 - 1, kx = k % 3 - 1;
            size_t obase = (((size_t)b * COFF + g * 18 + k * 2) * HH + h) * WW + w;
            float dy = offs[obase];
            float dx = offs[obase + (size_t)HW];
            float py = dy + (float)(h + ky);
            float px = dx + (float)(w + kx);
            float y0 = floorf(py), x0 = floorf(px);
            float fy = py - y0, fx = px - x0;
#pragma unroll
            for (int cn = 0; cn < 4; ++cn) {
                float yy = y0 + (float)(cn >> 1);
                float xx = x0 + (float)(cn & 1);
                float wy = (cn >> 1) ? fy : (1.f - fy);
                float wx = (cn & 1) ? fx : (1.f - fx);
                bool valid = (yy >= 0.f) && (yy < (float)HH) &&
                             (xx >= 0.f) && (xx < (float)WW);
                int yi = (int)fminf(fmaxf(yy, 0.f), (float)(HH - 1));
                int xi = (int)fminf(fmaxf(xx, 0.f), (float)(WW - 1));
                sidx[cn][w] = yi * WW + xi;
                swgt[cn][w] = valid ? (wy * wx) : 0.f;
            }
        }
        for (int i = t; i < CG * CG; i += 256) {
            int o = i >> 6, c = i & 63;
            wt2[c][o] = w_def[((size_t)(g * CG + o) * CG + c) * 9 + k];
        }
        __syncthreads();

        int   i0 = sidx[0][w], i1 = sidx[1][w], i2 = sidx[2][w], i3 = sidx[3][w];
        float g0 = swgt[0][w], g1 = swgt[1][w], g2 = swgt[2][w], g3 = swgt[3][w];
#pragma unroll
        for (int j = 0; j < 16; ++j) {
            int c = q * 16 + j;
            const float* xc = xg + (size_t)c * HW;
            float v = g0 * xc[i0] + g1 * xc[i1] + g2 * xc[i2] + g3 * xc[i3];
            vlds[c][w] = v;
        }
        __syncthreads();

#pragma unroll 4
        for (int c = 0; c < CG; ++c) {
            float xv = vlds[c][w];
#pragma unroll
            for (int j = 0; j < 16; ++j)
                acc[j] += xv * wt2[c][q * 16 + j];
        }
    }

#pragma unroll
    for (int j = 0; j < 16; ++j) {
        int o = q * 16 + j;
        out[(((size_t)b * CIN + g * CG + o) * HH + h) * WW + w] =
            acc[j] + b_def[g * CG + o];
    }
}

extern "C" void kernel_launch(void* const* d_in, const int* in_sizes, int n_in,
                              void* d_out, int out_size, void* d_ws, size_t ws_size,
                              hipStream_t stream) {
    const float* x     = (const float*)d_in[0];
    const float* w_off = (const float*)d_in[1];
    const float* b_off = (const float*)d_in[2];
    const float* w_def = (const float*)d_in[3];
    const float* b_def = (const float*)d_in[4];
    float* out = (float*)d_out;

    char* ws = (char*)d_ws;
    float*          offs = (float*)ws;
    unsigned short* wT3  = (unsigned short*)(ws + (size_t)OFFS_ELEMS * 4);
    unsigned short* woT3 = (unsigned short*)(ws + (size_t)OFFS_ELEMS * 4 + (size_t)WT_ELEMS * 2);
    unsigned short* xbf  = (unsigned short*)(ws + XBF_BYTE_OFF);

    if (ws_size >= NEED_NHWC) {
        int prep_elems = WT_ELEMS + WO3_ELEMS;
        prep_w_kernel<<<(prep_elems + 255) / 256, 256, 0, stream>>>(w_def, w_off, wT3, woT3);
        prep_x_kernel<<<BATCH * HH, 256, 0, stream>>>(x, xbf);
        conv_off_nhwc<<<BATCH * HH, 512, 0, stream>>>(xbf, woT3, b_off, offs);
        deform_nhwc<<<BATCH * OG * HH, 256, 0, stream>>>(xbf, offs, wT3, b_def, out);
    } else {
        conv_off_fb<<<BATCH * HH, 256, 0, stream>>>(x, w_off, b_off, offs);
        deform_fb<<<BATCH * OG * HH, 256, 0, stream>>>(x, offs, w_def, b_def, out);
    }
}

// Round 7
// 213.316 us; speedup vs baseline: 4.6048x; 1.1611x over previous
//
#include <hip/hip_runtime.h>
#include <hip/hip_bf16.h>

// Problem constants (B=8, C=256, H=W=64, OG=4, Cg=64, K=9, C_off=72)
#define BATCH 8
#define CIN   256
#define HH    64
#define WW    64
#define HW    4096
#define OG    4
#define CG    64
#define COFF  72

typedef __attribute__((ext_vector_type(8))) _Float16 half8;
typedef __attribute__((ext_vector_type(4))) float floatx4;

static __device__ __forceinline__ half8 splat8(float f) {
    _Float16 h = (_Float16)f;
    return (half8){h, h, h, h, h, h, h, h};
}

// ws layout:
//   offs  fp32  [B][72][H][W]                       bytes [0, 9437184)
//   wT3   fp16  fragment-order deform weights       bytes [9437184, 9732096)
//   woT3  fp16  fragment-order offset-conv weights  bytes [9732096, 10100736)
//   xh    fp16  [b][y][x][c]  NHWC  (8*4096*256)    bytes [10100736, 26877952)
#define OFFS_ELEMS (BATCH * COFF * HH * WW)      // 2359296
#define WT_ELEMS   (OG * 9 * 4 * 2 * 64 * 8)     // 147456
#define WO3_ELEMS  (8 * 9 * 5 * 64 * 8)          // 184320
#define XH_BYTE_OFF ((size_t)OFFS_ELEMS * 4 + (size_t)WT_ELEMS * 2 + (size_t)WO3_ELEMS * 2)
#define NEED_NHWC (XH_BYTE_OFF + (size_t)BATCH * HW * CIN * 2)   // 26877952

// ---------------------------------------------------------------------------
// Prep A: weights -> MFMA-fragment order, fp16 (lane-major => coalesced).
// ---------------------------------------------------------------------------
__global__ __launch_bounds__(256) void prep_w_kernel(
    const float* __restrict__ w_def, const float* __restrict__ w_off,
    _Float16* __restrict__ wT3, _Float16* __restrict__ woT3)
{
    int i = blockIdx.x * 256 + threadIdx.x;
    if (i < WT_ELEMS) {
        int j = i & 7;
        int l = (i >> 3) & 63;
        int rest = i >> 9;        // ((g*9+k)*4+mt)*2+kh
        int kh = rest & 1;
        int mt = (rest >> 1) & 3;
        int gk = rest >> 3;       // g*9+k
        int k = gk % 9, g = gk / 9;
        int o = mt * 16 + (l & 15);
        int c = kh * 32 + (l >> 4) * 8 + j;
        wT3[i] = (_Float16)w_def[((size_t)((g * CG + o) * CG + c)) * 9 + k];
    } else if (i < WT_ELEMS + WO3_ELEMS) {
        int idx = i - WT_ELEMS;
        int j = idx & 7;
        int l = (idx >> 3) & 63;
        int rest = idx >> 9;      // (chunk*9+tap)*5 + mt
        int mt = rest % 5;
        int ct = rest / 5;
        int tap = ct % 9, chunk = ct / 9;
        int o = mt * 16 + (l & 15);
        int c = chunk * 32 + (l >> 4) * 8 + j;
        float v = (o < COFF) ? w_off[((size_t)(o * CIN + c)) * 9 + tap] : 0.f;
        woT3[idx] = (_Float16)v;
    }
}

// ---------------------------------------------------------------------------
// Prep B: x NCHW fp32 -> NHWC fp16.  grid = B*H blocks, one (b,y) row each.
// ---------------------------------------------------------------------------
__global__ __launch_bounds__(256) void prep_x_kernel(
    const float* __restrict__ x, _Float16* __restrict__ xh)
{
    const int b = blockIdx.x >> 6;
    const int y = blockIdx.x & 63;
    const int t = threadIdx.x;

    __shared__ short tile[64][258];   // [px][c] bit-pattern of fp16

#pragma unroll
    for (int it = 0; it < 16; ++it) {
        int i  = t + it * 256;        // i < 4096
        int c  = i >> 4;
        int p4 = (i & 15) << 2;
        float4 v = *(const float4*)(x + (((size_t)(b * CIN + c)) << 12) + (y << 6) + p4);
        tile[p4 + 0][c] = __builtin_bit_cast(short, (_Float16)v.x);
        tile[p4 + 1][c] = __builtin_bit_cast(short, (_Float16)v.y);
        tile[p4 + 2][c] = __builtin_bit_cast(short, (_Float16)v.z);
        tile[p4 + 3][c] = __builtin_bit_cast(short, (_Float16)v.w);
    }
    __syncthreads();

    _Float16* dst = xh + (((size_t)(b * HW)) << 8) + ((size_t)(y * WW) << 8);
#pragma unroll
    for (int k = 0; k < 8; ++k) {
        int i  = t + k * 256;         // i < 2048
        int p  = i >> 5;
        int c8 = (i & 31) << 3;
        const unsigned* tp = (const unsigned*)&tile[p][c8];
        uint4 r = make_uint4(tp[0], tp[1], tp[2], tp[3]);
        *(uint4*)(dst + ((size_t)p << 8) + c8) = r;
    }
}

// ---------------------------------------------------------------------------
// Kernel 1 (NHWC fp16): offsets = conv3x3(x) + b_off. Implicit-GEMM MFMA f16.
// 512 threads = 8 waves: waves 0-3 do M-tiles {0,1,2}, waves 4-7 do {3,4}.
// ---------------------------------------------------------------------------
__global__ __launch_bounds__(512) void conv_off_nhwc(
    const _Float16* __restrict__ xh, const _Float16* __restrict__ woT3,
    const float* __restrict__ b_off, float* __restrict__ offs)
{
    const int b = blockIdx.x >> 6;
    const int h = blockIdx.x & 63;
    const int t = threadIdx.x;
    const int wv = t >> 6;
    const int l  = t & 63;
    const int lane16 = l & 15;
    const int quad   = l >> 4;
    const int pg = wv & 3;
    const int mh = wv >> 2;
    const int p  = pg * 16 + lane16;
    const int mt0 = mh ? 3 : 0;
    const int nmt = mh ? 2 : 3;

    __shared__ _Float16 xs[3][66][48];   // stride 48 halves = 96B, 16B-aligned

    floatx4 acc[3];
#pragma unroll
    for (int m = 0; m < 3; ++m) acc[m] = (floatx4){0.f, 0.f, 0.f, 0.f};

    // zero halo records (records 0 and 65 of each row) once
    if (t < 24) {
        int row = t >> 3;               // 0..2
        int rec = (t & 4) ? 65 : 0;
        int sub = t & 3;
        *(uint4*)&xs[row][rec][sub * 8] = make_uint4(0, 0, 0, 0);
    }

    for (int chunk = 0; chunk < 8; ++chunk) {
        __syncthreads();
        // stage 3 rows x 64 records x 64B (this chunk's 32 channels); 768 uint4
        for (int s = t; s < 768; s += 512) {
            int sub = s & 3;
            int rec = (s >> 2) & 63;
            int ky  = s >> 8;
            int yy = h + ky - 1;
            uint4 v = make_uint4(0, 0, 0, 0);
            if ((unsigned)yy < 64u)
                v = *(const uint4*)(xh + (((size_t)(b * HW + (yy << 6) + rec)) << 8)
                                       + chunk * 32 + sub * 8);
            *(uint4*)&xs[ky][rec + 1][sub * 8] = v;
        }
        __syncthreads();

#pragma unroll
        for (int tap = 0; tap < 9; ++tap) {
            const int ky = tap / 3, kx = tap % 3;
            half8 bfrag = *(const half8*)&xs[ky][p + kx][quad * 8];
            const _Float16* ab =
                woT3 + ((size_t)((chunk * 9 + tap) * 5 + mt0)) * 512 + l * 8;
            for (int m = 0; m < nmt; ++m) {
                half8 afrag = *(const half8*)(ab + m * 512);
                acc[m] = __builtin_amdgcn_mfma_f32_16x16x32_f16(afrag, bfrag, acc[m], 0, 0, 0);
            }
        }
    }

    for (int m = 0; m < nmt; ++m) {
#pragma unroll
        for (int rg = 0; rg < 4; ++rg) {
            int oc = (mt0 + m) * 16 + quad * 4 + rg;
            if (oc < COFF)
                offs[((size_t)(b * COFF + oc) << 12) + (h << 6) + p] =
                    acc[m][rg] + b_off[oc];
        }
    }
}

// ---------------------------------------------------------------------------
// Kernel 2 (NHWC fp16): deformable conv via MFMA f16 with LDS gather window.
// Stage rows h-2..h+2 of this (b,g) in LDS once (45KB, stride 72 halves =>
// uniform conflict-free banking); all bilinear gathers become ds_read_b128.
// Blend in packed fp16 (v_pk_fma_f16). Per-lane global fallback if a sample
// falls outside the window (correct for arbitrary offsets; ~never taken).
// One __syncthreads per block; no per-tap barriers.
// ---------------------------------------------------------------------------
__global__ __launch_bounds__(256) void deform_nhwc(
    const _Float16* __restrict__ xh, const float* __restrict__ offs,
    const _Float16* __restrict__ wT3, const float* __restrict__ b_def,
    float* __restrict__ out)
{
    const int h  = blockIdx.x & 63;
    const int bg = blockIdx.x >> 6;
    const int g  = bg & 3;
    const int b  = bg >> 2;
    const int t  = threadIdx.x;
    const int wv = t >> 6;
    const int l  = t & 63;
    const int lane16 = l & 15;
    const int quad   = l >> 4;
    const int p = wv * 16 + lane16;

    __shared__ _Float16 ls[5 * 64 * 72];   // [winrow][px][ch], 46080B

    floatx4 acc[4];
#pragma unroll
    for (int mt = 0; mt < 4; ++mt) acc[mt] = (floatx4){0.f, 0.f, 0.f, 0.f};

    // ---- stage 5-row window (rows h-2..h+2, group g's 64 channels) ----
#pragma unroll
    for (int it = 0; it < 10; ++it) {
        int id  = it * 256 + t;          // < 2560
        int c16 = id & 7;
        int px  = (id >> 3) & 63;
        int r   = id >> 9;               // 0..4
        int r_img = h - 2 + r;
        uint4 v = make_uint4(0, 0, 0, 0);
        if ((unsigned)r_img < 64u)
            v = *(const uint4*)(xh + (((size_t)(b * HW + (r_img << 6) + px)) << 8)
                                   + g * 64 + c16 * 8);
        *(uint4*)&ls[(r * 64 + px) * 72 + c16 * 8] = v;
    }

    // prefetch all 18 offset values for this pixel
    float dyv[9], dxv[9];
    {
        const float* ofb = offs + (((size_t)(b * COFF + g * 18)) * HH + h) * WW + p;
#pragma unroll
        for (int k = 0; k < 9; ++k) {
            dyv[k] = ofb[(size_t)(2 * k) * HW];
            dxv[k] = ofb[(size_t)(2 * k + 1) * HW];
        }
    }

    __syncthreads();

    const _Float16* xg = xh + (((size_t)(b * HW)) << 8) + g * 64;

#pragma unroll
    for (int k = 0; k < 9; ++k) {
        // ---- bilinear params ----
        float py = dyv[k] + (float)(h + (k / 3) - 1);
        float px_ = dxv[k] + (float)(p + (k % 3) - 1);
        float y0f = floorf(py), x0f = floorf(px_);
        float fy = py - y0f, fx = px_ - x0f;
        int y0 = (int)y0f, x0 = (int)x0f;
        float wy0 = ((y0 >= 0) & (y0 < HH)) ? (1.f - fy) : 0.f;
        float wy1 = ((y0 >= -1) & (y0 < HH - 1)) ? fy : 0.f;
        float wx0 = ((x0 >= 0) & (x0 < WW)) ? (1.f - fx) : 0.f;
        float wx1 = ((x0 >= -1) & (x0 < WW - 1)) ? fx : 0.f;
        int yia = min(max(y0, 0), HH - 1), yib = min(max(y0 + 1, 0), HH - 1);
        int xia = min(max(x0, 0), WW - 1), xib = min(max(x0 + 1, 0), WW - 1);
        bool inWin = (y0 >= h - 2) & (y0 <= h + 1);

        const int co = quad * 8;
        int wa = min(max(yia - (h - 2), 0), 4);
        int wb = min(max(yib - (h - 2), 0), 4);
        const _Float16* pa = ls + ((wa * 64 + xia) * 72);
        const _Float16* pb = ls + ((wa * 64 + xib) * 72);
        const _Float16* pc = ls + ((wb * 64 + xia) * 72);
        const _Float16* pd = ls + ((wb * 64 + xib) * 72);

        half8 aL = *(const half8*)(pa + co);
        half8 bL = *(const half8*)(pb + co);
        half8 cL = *(const half8*)(pc + co);
        half8 dL = *(const half8*)(pd + co);
        half8 aH = *(const half8*)(pa + co + 32);
        half8 bH = *(const half8*)(pb + co + 32);
        half8 cH = *(const half8*)(pc + co + 32);
        half8 dH = *(const half8*)(pd + co + 32);

        if (!inWin) {   // rare: sample escaped the staged window
            const _Float16* qa = xg + (((size_t)((yia << 6) + xia)) << 8);
            const _Float16* qb = xg + (((size_t)((yia << 6) + xib)) << 8);
            const _Float16* qc = xg + (((size_t)((yib << 6) + xia)) << 8);
            const _Float16* qd = xg + (((size_t)((yib << 6) + xib)) << 8);
            aL = *(const half8*)(qa + co);  aH = *(const half8*)(qa + co + 32);
            bL = *(const half8*)(qb + co);  bH = *(const half8*)(qb + co + 32);
            cL = *(const half8*)(qc + co);  cH = *(const half8*)(qc + co + 32);
            dL = *(const half8*)(qd + co);  dH = *(const half8*)(qd + co + 32);
        }

        // ---- packed fp16 blend ----
        half8 W00 = splat8(wy0 * wx0), W01 = splat8(wy0 * wx1);
        half8 W10 = splat8(wy1 * wx0), W11 = splat8(wy1 * wx1);
        half8 f0 = aL * W00 + bL * W01 + cL * W10 + dL * W11;
        half8 f1 = aH * W00 + bH * W01 + cH * W10 + dH * W11;

        // ---- A-frags: coalesced from fragment-order wT3 + MFMA ----
        const _Float16* wk = wT3 + ((size_t)(g * 9 + k) << 12) + l * 8;
#pragma unroll
        for (int mt = 0; mt < 4; ++mt) {
            half8 a0 = *(const half8*)(wk + (mt * 2 + 0) * 512);
            half8 a1 = *(const half8*)(wk + (mt * 2 + 1) * 512);
            acc[mt] = __builtin_amdgcn_mfma_f32_16x16x32_f16(a0, f0, acc[mt], 0, 0, 0);
            acc[mt] = __builtin_amdgcn_mfma_f32_16x16x32_f16(a1, f1, acc[mt], 0, 0, 0);
        }
    }

#pragma unroll
    for (int mt = 0; mt < 4; ++mt) {
#pragma unroll
        for (int rg = 0; rg < 4; ++rg) {
            int o = mt * 16 + quad * 4 + rg;
            float v = acc[mt][rg] + b_def[g * CG + o];
            out[((size_t)(b * CIN + g * CG + o) * HH + h) * WW + p] = v;
        }
    }
}

// ===========================================================================
// FALLBACK PATH (ws too small for xh): fp32 correctness-first (not expected
// to be taken -- ws has been >= 26.9MB in all rounds).
// ===========================================================================
__global__ __launch_bounds__(256) void conv_off_fb(
    const float* __restrict__ x, const float* __restrict__ w_off,
    const float* __restrict__ b_off, float* __restrict__ offs)
{
    const int b = blockIdx.x >> 6;
    const int h = blockIdx.x & 63;
    const int t = threadIdx.x;
    const int w = t & 63;
    const int q = t >> 6;

    __shared__ float xsf[3][8][WW + 2];
    __shared__ float wtf[9][8][COFF];

    float acc[18];
#pragma unroll
    for (int j = 0; j < 18; ++j) acc[j] = 0.f;

    for (int c0 = 0; c0 < CIN; c0 += 8) {
        __syncthreads();
        for (int i = t; i < 3 * 8 * (WW + 2); i += 256) {
            int wp = i % (WW + 2);
            int rem = i / (WW + 2);
            int cc = rem % 8;
            int ky = rem / 8;
            int yy = h + ky - 1;
            int xx = wp - 1;
            float v = 0.f;
            if (yy >= 0 && yy < HH && xx >= 0 && xx < WW)
                v = x[(((size_t)b * CIN + c0 + cc) * HH + yy) * WW + xx];
            xsf[ky][cc][wp] = v;
        }
        for (int i = t; i < 9 * 8 * COFF; i += 256) {
            int oc = i % COFF;
            int rem = i / COFF;
            int cc = rem % 8;
            int tap = rem / 8;
            wtf[tap][cc][oc] = w_off[((size_t)oc * CIN + c0 + cc) * 9 + tap];
        }
        __syncthreads();
        for (int tap = 0; tap < 9; ++tap) {
            const int ky = tap / 3, kx = tap % 3;
#pragma unroll
            for (int cc = 0; cc < 8; ++cc) {
                float xv = xsf[ky][cc][w + kx];
#pragma unroll
                for (int j = 0; j < 18; ++j)
                    acc[j] += xv * wtf[tap][cc][q * 18 + j];
            }
        }
    }
#pragma unroll
    for (int j = 0; j < 18; ++j) {
        int oc = q * 18 + j;
        offs[(((size_t)b * COFF + oc) * HH + h) * WW + w] = acc[j] + b_off[oc];
    }
}

__global__ __launch_bounds__(256) void deform_fb(
    const float* __restrict__ x, const float* __restrict__ offs,
    const float* __restrict__ w_def, const float* __restrict__ b_def,
    float* __restrict__ out)
{
    const int h  = blockIdx.x & 63;
    const int bg = blockIdx.x >> 6;
    const int g  = bg & 3;
    const int b  = bg >> 2;
    const int t  = threadIdx.x;
    const int w  = t & 63;
    const int q  = t >> 6;

    __shared__ float vlds[CG][WW];
    __shared__ float wt2[CG][CG];
    __shared__ int   sidx[4][WW];
    __shared__ float swgt[4][WW];

    float acc[16];
#pragma unroll
    for (int j = 0; j < 16; ++j) acc[j] = 0.f;

    const float* xg = x + ((size_t)(b * CIN + g * CG)) * HW;

    for (int k = 0; k < 9; ++k) {
        __syncthreads();
        if (t < 64) {
            const int ky = k / 3 - 1, kx = k % 3 - 1;
            size_t obase = (((size_t)b * COFF + g * 18 + k * 2) * HH + h) * WW + w;
            float dy = offs[obase];
            float dx = offs[obase + (size_t)HW];
            float py = dy + (float)(h + ky);
            float px = dx + (float)(w + kx);
            float y0 = floorf(py), x0 = floorf(px);
            float fy = py - y0, fx = px - x0;
#pragma unroll
            for (int cn = 0; cn < 4; ++cn) {
                float yy = y0 + (float)(cn >> 1);
                float xx = x0 + (float)(cn & 1);
                float wy = (cn >> 1) ? fy : (1.f - fy);
                float wx = (cn & 1) ? fx : (1.f - fx);
                bool valid = (yy >= 0.f) && (yy < (float)HH) &&
                             (xx >= 0.f) && (xx < (float)WW);
                int yi = (int)fminf(fmaxf(yy, 0.f), (float)(HH - 1));
                int xi = (int)fminf(fmaxf(xx, 0.f), (float)(WW - 1));
                sidx[cn][w] = yi * WW + xi;
                swgt[cn][w] = valid ? (wy * wx) : 0.f;
            }
        }
        for (int i = t; i < CG * CG; i += 256) {
            int o = i >> 6, c = i & 63;
            wt2[c][o] = w_def[((size_t)(g * CG + o) * CG + c) * 9 + k];
        }
        __syncthreads();

        int   i0 = sidx[0][w], i1 = sidx[1][w], i2 = sidx[2][w], i3 = sidx[3][w];
        float g0 = swgt[0][w], g1 = swgt[1][w], g2 = swgt[2][w], g3 = swgt[3][w];
#pragma unroll
        for (int j = 0; j < 16; ++j) {
            int c = q * 16 + j;
            const float* xc = xg + (size_t)c * HW;
            float v = g0 * xc[i0] + g1 * xc[i1] + g2 * xc[i2] + g3 * xc[i3];
            vlds[c][w] = v;
        }
        __syncthreads();

#pragma unroll 4
        for (int c = 0; c < CG; ++c) {
            float xv = vlds[c][w];
#pragma unroll
            for (int j = 0; j < 16; ++j)
                acc[j] += xv * wt2[c][q * 16 + j];
        }
    }

#pragma unroll
    for (int j = 0; j < 16; ++j) {
        int o = q * 16 + j;
        out[(((size_t)b * CIN + g * CG + o) * HH + h) * WW + w] =
            acc[j] + b_def[g * CG + o];
    }
}

extern "C" void kernel_launch(void* const* d_in, const int* in_sizes, int n_in,
                              void* d_out, int out_size, void* d_ws, size_t ws_size,
                              hipStream_t stream) {
    const float* x     = (const float*)d_in[0];
    const float* w_off = (const float*)d_in[1];
    const float* b_off = (const float*)d_in[2];
    const float* w_def = (const float*)d_in[3];
    const float* b_def = (const float*)d_in[4];
    float* out = (float*)d_out;

    char* ws = (char*)d_ws;
    float*     offs = (float*)ws;
    _Float16*  wT3  = (_Float16*)(ws + (size_t)OFFS_ELEMS * 4);
    _Float16*  woT3 = (_Float16*)(ws + (size_t)OFFS_ELEMS * 4 + (size_t)WT_ELEMS * 2);
    _Float16*  xh   = (_Float16*)(ws + XH_BYTE_OFF);

    if (ws_size >= NEED_NHWC) {
        int prep_elems = WT_ELEMS + WO3_ELEMS;
        prep_w_kernel<<<(prep_elems + 255) / 256, 256, 0, stream>>>(w_def, w_off, wT3, woT3);
        prep_x_kernel<<<BATCH * HH, 256, 0, stream>>>(x, xh);
        conv_off_nhwc<<<BATCH * HH, 512, 0, stream>>>(xh, woT3, b_off, offs);
        deform_nhwc<<<BATCH * OG * HH, 256, 0, stream>>>(xh, offs, wT3, b_def, out);
    } else {
        conv_off_fb<<<BATCH * HH, 256, 0, stream>>>(x, w_off, b_off, offs);
        deform_fb<<<BATCH * OG * HH, 256, 0, stream>>>(x, offs, w_def, b_def, out);
    }
}

// Round 8
// 188.115 us; speedup vs baseline: 5.2216x; 1.1340x over previous
//
#include <hip/hip_runtime.h>
#include <hip/hip_bf16.h>

// Problem constants (B=8, C=256, H=W=64, OG=4, Cg=64, K=9, C_off=72)
#define BATCH 8
#define CIN   256
#define HH    64
#define WW    64
#define HW    4096
#define OG    4
#define CG    64
#define COFF  72

typedef __attribute__((ext_vector_type(8))) _Float16 half8;
typedef __attribute__((ext_vector_type(4))) float floatx4;

static __device__ __forceinline__ half8 splat8(float f) {
    _Float16 h = (_Float16)f;
    return (half8){h, h, h, h, h, h, h, h};
}

// ws layout:
//   offs  fp32  [B][72][H][W]                       bytes [0, 9437184)
//   wT3   fp16  fragment-order deform weights       bytes [9437184, 9732096)
//   woT3  fp16  fragment-order offset-conv weights  bytes [9732096, 10100736)
//   xh    fp16  [b][y][x][c]  NHWC  (8*4096*256)    bytes [10100736, 26877952)
#define OFFS_ELEMS (BATCH * COFF * HH * WW)      // 2359296
#define WT_ELEMS   (OG * 9 * 4 * 2 * 64 * 8)     // 147456
#define WO3_ELEMS  (8 * 9 * 5 * 64 * 8)          // 184320
#define XH_BYTE_OFF ((size_t)OFFS_ELEMS * 4 + (size_t)WT_ELEMS * 2 + (size_t)WO3_ELEMS * 2)
#define NEED_NHWC (XH_BYTE_OFF + (size_t)BATCH * HW * CIN * 2)   // 26877952

// ---------------------------------------------------------------------------
// Prep A: weights -> MFMA-fragment order, fp16 (lane-major => coalesced).
// ---------------------------------------------------------------------------
__global__ __launch_bounds__(256) void prep_w_kernel(
    const float* __restrict__ w_def, const float* __restrict__ w_off,
    _Float16* __restrict__ wT3, _Float16* __restrict__ woT3)
{
    int i = blockIdx.x * 256 + threadIdx.x;
    if (i < WT_ELEMS) {
        int j = i & 7;
        int l = (i >> 3) & 63;
        int rest = i >> 9;        // ((g*9+k)*4+mt)*2+kh
        int kh = rest & 1;
        int mt = (rest >> 1) & 3;
        int gk = rest >> 3;       // g*9+k
        int k = gk % 9, g = gk / 9;
        int o = mt * 16 + (l & 15);
        int c = kh * 32 + (l >> 4) * 8 + j;
        wT3[i] = (_Float16)w_def[((size_t)((g * CG + o) * CG + c)) * 9 + k];
    } else if (i < WT_ELEMS + WO3_ELEMS) {
        int idx = i - WT_ELEMS;
        int j = idx & 7;
        int l = (idx >> 3) & 63;
        int rest = idx >> 9;      // (chunk*9+tap)*5 + mt
        int mt = rest % 5;
        int ct = rest / 5;
        int tap = ct % 9, chunk = ct / 9;
        int o = mt * 16 + (l & 15);
        int c = chunk * 32 + (l >> 4) * 8 + j;
        float v = (o < COFF) ? w_off[((size_t)(o * CIN + c)) * 9 + tap] : 0.f;
        woT3[idx] = (_Float16)v;
    }
}

// ---------------------------------------------------------------------------
// Prep B: x NCHW fp32 -> NHWC fp16.  grid = B*H blocks, one (b,y) row each.
// ---------------------------------------------------------------------------
__global__ __launch_bounds__(256) void prep_x_kernel(
    const float* __restrict__ x, _Float16* __restrict__ xh)
{
    const int b = blockIdx.x >> 6;
    const int y = blockIdx.x & 63;
    const int t = threadIdx.x;

    __shared__ short tile[64][258];   // [px][c] bit-pattern of fp16

#pragma unroll
    for (int it = 0; it < 16; ++it) {
        int i  = t + it * 256;        // i < 4096
        int c  = i >> 4;
        int p4 = (i & 15) << 2;
        float4 v = *(const float4*)(x + (((size_t)(b * CIN + c)) << 12) + (y << 6) + p4);
        tile[p4 + 0][c] = __builtin_bit_cast(short, (_Float16)v.x);
        tile[p4 + 1][c] = __builtin_bit_cast(short, (_Float16)v.y);
        tile[p4 + 2][c] = __builtin_bit_cast(short, (_Float16)v.z);
        tile[p4 + 3][c] = __builtin_bit_cast(short, (_Float16)v.w);
    }
    __syncthreads();

    _Float16* dst = xh + (((size_t)(b * HW)) << 8) + ((size_t)(y * WW) << 8);
#pragma unroll
    for (int k = 0; k < 8; ++k) {
        int i  = t + k * 256;         // i < 2048
        int p  = i >> 5;
        int c8 = (i & 31) << 3;
        const unsigned* tp = (const unsigned*)&tile[p][c8];
        uint4 r = make_uint4(tp[0], tp[1], tp[2], tp[3]);
        *(uint4*)(dst + ((size_t)p << 8) + c8) = r;
    }
}

// ---------------------------------------------------------------------------
// Kernel 1 (NHWC fp16): offsets = conv3x3(x) + b_off. Implicit-GEMM MFMA f16.
// 512 threads = 8 waves: waves 0-3 M-tiles {0,1,2}, waves 4-7 {3,4}.
// A-chunk (45KB) AND B-rows (16KB) staged in LDS per chunk with register
// prefetch of the next chunk; A-frag reads become conflict-free ds_read_b128
// (kills the redundant 16-line-per-instr global A reads that were the wall).
// ---------------------------------------------------------------------------
__global__ __launch_bounds__(512) void conv_off_nhwc(
    const _Float16* __restrict__ xh, const _Float16* __restrict__ woT3,
    const float* __restrict__ b_off, float* __restrict__ offs)
{
    const int b = blockIdx.x >> 6;
    const int h = blockIdx.x & 63;
    const int t = threadIdx.x;
    const int wv = t >> 6;
    const int l  = t & 63;
    const int lane16 = l & 15;
    const int quad   = l >> 4;
    const int pg = wv & 3;
    const int mh = wv >> 2;
    const int p  = pg * 16 + lane16;
    const int mt0 = mh ? 3 : 0;
    const int nmt = mh ? 2 : 3;

    __shared__ _Float16 xs[3][66][40];   // 15840 B, stride 80B => 2-way (free)
    __shared__ _Float16 wa[45 * 512];    // 46080 B, lane-major (conflict-free)

    floatx4 acc[3];
#pragma unroll
    for (int m = 0; m < 3; ++m) acc[m] = (floatx4){0.f, 0.f, 0.f, 0.f};

    // zero halo records (records 0 and 65 of each row) once
    if (t < 24) {
        int row = t >> 3;               // 0..2
        int rec = (t & 4) ? 65 : 0;
        int sub = t & 3;
        *(uint4*)&xs[row][rec][sub * 8] = make_uint4(0, 0, 0, 0);
    }

    uint4 ra[6], rb[2];
    auto issue = [&](int chunk) {
        const uint4* asrc = (const uint4*)(woT3 + (size_t)chunk * 45 * 512);
#pragma unroll
        for (int it = 0; it < 6; ++it) {
            int i = t + it * 512;
            ra[it] = (i < 2880) ? asrc[i] : make_uint4(0, 0, 0, 0);
        }
#pragma unroll
        for (int it = 0; it < 2; ++it) {
            int i = t + it * 512;
            int sub = i & 3, rec = (i >> 2) & 63, ky = i >> 8;
            int yy = h + ky - 1;
            uint4 v = make_uint4(0, 0, 0, 0);
            if (i < 768 && (unsigned)yy < 64u)
                v = *(const uint4*)(xh + (((size_t)(b * HW + (yy << 6) + rec)) << 8)
                                       + chunk * 32 + sub * 8);
            rb[it] = v;
        }
    };
    auto commit = [&]() {
#pragma unroll
        for (int it = 0; it < 6; ++it) {
            int i = t + it * 512;
            if (i < 2880) *(uint4*)&wa[i * 8] = ra[it];
        }
#pragma unroll
        for (int it = 0; it < 2; ++it) {
            int i = t + it * 512;
            if (i < 768) {
                int sub = i & 3, rec = (i >> 2) & 63, ky = i >> 8;
                *(uint4*)&xs[ky][rec + 1][sub * 8] = rb[it];
            }
        }
    };

    issue(0);
    commit();
    __syncthreads();

    for (int chunk = 0; chunk < 8; ++chunk) {
        if (chunk < 7) issue(chunk + 1);   // loads in flight across compute

#pragma unroll
        for (int tap = 0; tap < 9; ++tap) {
            const int ky = tap / 3, kx = tap % 3;
            half8 bfrag = *(const half8*)&xs[ky][p + kx][quad * 8];
            const _Float16* ab = wa + (size_t)(tap * 5 + mt0) * 512 + l * 8;
            for (int m = 0; m < nmt; ++m) {
                half8 afrag = *(const half8*)(ab + m * 512);
                acc[m] = __builtin_amdgcn_mfma_f32_16x16x32_f16(afrag, bfrag, acc[m], 0, 0, 0);
            }
        }

        if (chunk < 7) {
            __syncthreads();   // all reads of current LDS done
            commit();
            __syncthreads();   // new LDS visible
        }
    }

    for (int m = 0; m < nmt; ++m) {
#pragma unroll
        for (int rg = 0; rg < 4; ++rg) {
            int oc = (mt0 + m) * 16 + quad * 4 + rg;
            if (oc < COFF)
                offs[((size_t)(b * COFF + oc) << 12) + (h << 6) + p] =
                    acc[m][rg] + b_off[oc];
        }
    }
}

// ---------------------------------------------------------------------------
// Kernel 2 (NHWC fp16): deformable conv via MFMA f16, LDS gather window PLUS
// per-tap double-buffered A tile in LDS (8KB x2) with register prefetch:
// all per-tap traffic (gathers + A-frags) is LDS; one barrier per tap.
// ---------------------------------------------------------------------------
__global__ __launch_bounds__(256) void deform_nhwc(
    const _Float16* __restrict__ xh, const float* __restrict__ offs,
    const _Float16* __restrict__ wT3, const float* __restrict__ b_def,
    float* __restrict__ out)
{
    const int h  = blockIdx.x & 63;
    const int bg = blockIdx.x >> 6;
    const int g  = bg & 3;
    const int b  = bg >> 2;
    const int t  = threadIdx.x;
    const int wv = t >> 6;
    const int l  = t & 63;
    const int lane16 = l & 15;
    const int quad   = l >> 4;
    const int p = wv * 16 + lane16;

    __shared__ _Float16 ls[5 * 64 * 72];    // gather window, 46080 B
    __shared__ _Float16 wa2[2][4096];       // per-tap A dbuf, 2 x 8192 B

    floatx4 acc[4];
#pragma unroll
    for (int mt = 0; mt < 4; ++mt) acc[mt] = (floatx4){0.f, 0.f, 0.f, 0.f};

    // ---- stage 5-row window (rows h-2..h+2, group g's 64 channels) ----
#pragma unroll
    for (int it = 0; it < 10; ++it) {
        int id  = it * 256 + t;          // < 2560
        int c16 = id & 7;
        int px  = (id >> 3) & 63;
        int r   = id >> 9;               // 0..4
        int r_img = h - 2 + r;
        uint4 v = make_uint4(0, 0, 0, 0);
        if ((unsigned)r_img < 64u)
            v = *(const uint4*)(xh + (((size_t)(b * HW + (r_img << 6) + px)) << 8)
                                   + g * 64 + c16 * 8);
        *(uint4*)&ls[(r * 64 + px) * 72 + c16 * 8] = v;
    }

    // ---- stage tap-0 A tile (8KB = 512 uint4, 2 per thread) ----
    {
        const uint4* asrc = (const uint4*)(wT3 + ((size_t)(g * 9) << 12));
        uint4 a0 = asrc[t], a1 = asrc[t + 256];
        *(uint4*)&wa2[0][t * 8] = a0;
        *(uint4*)&wa2[0][(t + 256) * 8] = a1;
    }

    // prefetch all 18 offset values for this pixel
    float dyv[9], dxv[9];
    {
        const float* ofb = offs + (((size_t)(b * COFF + g * 18)) * HH + h) * WW + p;
#pragma unroll
        for (int k = 0; k < 9; ++k) {
            dyv[k] = ofb[(size_t)(2 * k) * HW];
            dxv[k] = ofb[(size_t)(2 * k + 1) * HW];
        }
    }

    __syncthreads();

    const _Float16* xg = xh + (((size_t)(b * HW)) << 8) + g * 64;

#pragma unroll
    for (int k = 0; k < 9; ++k) {
        // ---- prefetch next tap's A tile into registers ----
        uint4 pw0, pw1;
        if (k < 8) {
            const uint4* asrc = (const uint4*)(wT3 + ((size_t)(g * 9 + k + 1) << 12));
            pw0 = asrc[t];
            pw1 = asrc[t + 256];
        }

        // ---- bilinear params ----
        float py = dyv[k] + (float)(h + (k / 3) - 1);
        float px_ = dxv[k] + (float)(p + (k % 3) - 1);
        float y0f = floorf(py), x0f = floorf(px_);
        float fy = py - y0f, fx = px_ - x0f;
        int y0 = (int)y0f, x0 = (int)x0f;
        float wy0 = ((y0 >= 0) & (y0 < HH)) ? (1.f - fy) : 0.f;
        float wy1 = ((y0 >= -1) & (y0 < HH - 1)) ? fy : 0.f;
        float wx0 = ((x0 >= 0) & (x0 < WW)) ? (1.f - fx) : 0.f;
        float wx1 = ((x0 >= -1) & (x0 < WW - 1)) ? fx : 0.f;
        int yia = min(max(y0, 0), HH - 1), yib = min(max(y0 + 1, 0), HH - 1);
        int xia = min(max(x0, 0), WW - 1), xib = min(max(x0 + 1, 0), WW - 1);
        bool inWin = (y0 >= h - 2) & (y0 <= h + 1);

        const int co = quad * 8;
        int wa_ = min(max(yia - (h - 2), 0), 4);
        int wb_ = min(max(yib - (h - 2), 0), 4);
        const _Float16* pa = ls + ((wa_ * 64 + xia) * 72);
        const _Float16* pb = ls + ((wa_ * 64 + xib) * 72);
        const _Float16* pc = ls + ((wb_ * 64 + xia) * 72);
        const _Float16* pd = ls + ((wb_ * 64 + xib) * 72);

        half8 aL = *(const half8*)(pa + co);
        half8 bL = *(const half8*)(pb + co);
        half8 cL = *(const half8*)(pc + co);
        half8 dL = *(const half8*)(pd + co);
        half8 aH = *(const half8*)(pa + co + 32);
        half8 bH = *(const half8*)(pb + co + 32);
        half8 cH = *(const half8*)(pc + co + 32);
        half8 dH = *(const half8*)(pd + co + 32);

        if (!inWin) {   // rare: sample escaped the staged window
            const _Float16* qa = xg + (((size_t)((yia << 6) + xia)) << 8);
            const _Float16* qb = xg + (((size_t)((yia << 6) + xib)) << 8);
            const _Float16* qc = xg + (((size_t)((yib << 6) + xia)) << 8);
            const _Float16* qd = xg + (((size_t)((yib << 6) + xib)) << 8);
            aL = *(const half8*)(qa + co);  aH = *(const half8*)(qa + co + 32);
            bL = *(const half8*)(qb + co);  bH = *(const half8*)(qb + co + 32);
            cL = *(const half8*)(qc + co);  cH = *(const half8*)(qc + co + 32);
            dL = *(const half8*)(qd + co);  dH = *(const half8*)(qd + co + 32);
        }

        // ---- packed fp16 blend ----
        half8 W00 = splat8(wy0 * wx0), W01 = splat8(wy0 * wx1);
        half8 W10 = splat8(wy1 * wx0), W11 = splat8(wy1 * wx1);
        half8 f0 = aL * W00 + bL * W01 + cL * W10 + dL * W11;
        half8 f1 = aH * W00 + bH * W01 + cH * W10 + dH * W11;

        // ---- A-frags from LDS dbuf + MFMA ----
        const _Float16* wk = &wa2[k & 1][l * 8];
#pragma unroll
        for (int mt = 0; mt < 4; ++mt) {
            half8 a0 = *(const half8*)(wk + (mt * 2 + 0) * 512);
            half8 a1 = *(const half8*)(wk + (mt * 2 + 1) * 512);
            acc[mt] = __builtin_amdgcn_mfma_f32_16x16x32_f16(a0, f0, acc[mt], 0, 0, 0);
            acc[mt] = __builtin_amdgcn_mfma_f32_16x16x32_f16(a1, f1, acc[mt], 0, 0, 0);
        }

        // ---- commit next tap's A tile; single barrier per tap ----
        if (k < 8) {
            _Float16* dst = wa2[(k + 1) & 1];
            *(uint4*)&dst[t * 8] = pw0;
            *(uint4*)&dst[(t + 256) * 8] = pw1;
            __syncthreads();
        }
    }

#pragma unroll
    for (int mt = 0; mt < 4; ++mt) {
#pragma unroll
        for (int rg = 0; rg < 4; ++rg) {
            int o = mt * 16 + quad * 4 + rg;
            float v = acc[mt][rg] + b_def[g * CG + o];
            out[((size_t)(b * CIN + g * CG + o) * HH + h) * WW + p] = v;
        }
    }
}

// ===========================================================================
// FALLBACK PATH (ws too small for xh): fp32 correctness-first (not expected
// to be taken -- ws has been >= 26.9MB in all rounds).
// ===========================================================================
__global__ __launch_bounds__(256) void conv_off_fb(
    const float* __restrict__ x, const float* __restrict__ w_off,
    const float* __restrict__ b_off, float* __restrict__ offs)
{
    const int b = blockIdx.x >> 6;
    const int h = blockIdx.x & 63;
    const int t = threadIdx.x;
    const int w = t & 63;
    const int q = t >> 6;

    __shared__ float xsf[3][8][WW + 2];
    __shared__ float wtf[9][8][COFF];

    float acc[18];
#pragma unroll
    for (int j = 0; j < 18; ++j) acc[j] = 0.f;

    for (int c0 = 0; c0 < CIN; c0 += 8) {
        __syncthreads();
        for (int i = t; i < 3 * 8 * (WW + 2); i += 256) {
            int wp = i % (WW + 2);
            int rem = i / (WW + 2);
            int cc = rem % 8;
            int ky = rem / 8;
            int yy = h + ky - 1;
            int xx = wp - 1;
            float v = 0.f;
            if (yy >= 0 && yy < HH && xx >= 0 && xx < WW)
                v = x[(((size_t)b * CIN + c0 + cc) * HH + yy) * WW + xx];
            xsf[ky][cc][wp] = v;
        }
        for (int i = t; i < 9 * 8 * COFF; i += 256) {
            int oc = i % COFF;
            int rem = i / COFF;
            int cc = rem % 8;
            int tap = rem / 8;
            wtf[tap][cc][oc] = w_off[((size_t)oc * CIN + c0 + cc) * 9 + tap];
        }
        __syncthreads();
        for (int tap = 0; tap < 9; ++tap) {
            const int ky = tap / 3, kx = tap % 3;
#pragma unroll
            for (int cc = 0; cc < 8; ++cc) {
                float xv = xsf[ky][cc][w + kx];
#pragma unroll
                for (int j = 0; j < 18; ++j)
                    acc[j] += xv * wtf[tap][cc][q * 18 + j];
            }
        }
    }
#pragma unroll
    for (int j = 0; j < 18; ++j) {
        int oc = q * 18 + j;
        offs[(((size_t)b * COFF + oc) * HH + h) * WW + w] = acc[j] + b_off[oc];
    }
}

__global__ __launch_bounds__(256) void deform_fb(
    const float* __restrict__ x, const float* __restrict__ offs,
    const float* __restrict__ w_def, const float* __restrict__ b_def,
    float* __restrict__ out)
{
    const int h  = blockIdx.x & 63;
    const int bg = blockIdx.x >> 6;
    const int g  = bg & 3;
    const int b  = bg >> 2;
    const int t  = threadIdx.x;
    const int w  = t & 63;
    const int q  = t >> 6;

    __shared__ float vlds[CG][WW];
    __shared__ float wt2[CG][CG];
    __shared__ int   sidx[4][WW];
    __shared__ float swgt[4][WW];

    float acc[16];
#pragma unroll
    for (int j = 0; j < 16; ++j) acc[j] = 0.f;

    const float* xg = x + ((size_t)(b * CIN + g * CG)) * HW;

    for (int k = 0; k < 9; ++k) {
        __syncthreads();
        if (t < 64) {
            const int ky = k / 3 - 1, kx = k % 3 - 1;
            size_t obase = (((size_t)b * COFF + g * 18 + k * 2) * HH + h) * WW + w;
            float dy = offs[obase];
            float dx = offs[obase + (size_t)HW];
            float py = dy + (float)(h + ky);
            float px = dx + (float)(w + kx);
            float y0 = floorf(py), x0 = floorf(px);
            float fy = py - y0, fx = px - x0;
#pragma unroll
            for (int cn = 0; cn < 4; ++cn) {
                float yy = y0 + (float)(cn >> 1);
                float xx = x0 + (float)(cn & 1);
                float wy = (cn >> 1) ? fy : (1.f - fy);
                float wx = (cn & 1) ? fx : (1.f - fx);
                bool valid = (yy >= 0.f) && (yy < (float)HH) &&
                             (xx >= 0.f) && (xx < (float)WW);
                int yi = (int)fminf(fmaxf(yy, 0.f), (float)(HH - 1));
                int xi = (int)fminf(fmaxf(xx, 0.f), (float)(WW - 1));
                sidx[cn][w] = yi * WW + xi;
                swgt[cn][w] = valid ? (wy * wx) : 0.f;
            }
        }
        for (int i = t; i < CG * CG; i += 256) {
            int o = i >> 6, c = i & 63;
            wt2[c][o] = w_def[((size_t)(g * CG + o) * CG + c) * 9 + k];
        }
        __syncthreads();

        int   i0 = sidx[0][w], i1 = sidx[1][w], i2 = sidx[2][w], i3 = sidx[3][w];
        float g0 = swgt[0][w], g1 = swgt[1][w], g2 = swgt[2][w], g3 = swgt[3][w];
#pragma unroll
        for (int j = 0; j < 16; ++j) {
            int c = q * 16 + j;
            const float* xc = xg + (size_t)c * HW;
            float v = g0 * xc[i0] + g1 * xc[i1] + g2 * xc[i2] + g3 * xc[i3];
            vlds[c][w] = v;
        }
        __syncthreads();

#pragma unroll 4
        for (int c = 0; c < CG; ++c) {
            float xv = vlds[c][w];
#pragma unroll
            for (int j = 0; j < 16; ++j)
                acc[j] += xv * wt2[c][q * 16 + j];
        }
    }

#pragma unroll
    for (int j = 0; j < 16; ++j) {
        int o = q * 16 + j;
        out[(((size_t)b * CIN + g * CG + o) * HH + h) * WW + w] =
            acc[j] + b_def[g * CG + o];
    }
}

extern "C" void kernel_launch(void* const* d_in, const int* in_sizes, int n_in,
                              void* d_out, int out_size, void* d_ws, size_t ws_size,
                              hipStream_t stream) {
    const float* x     = (const float*)d_in[0];
    const float* w_off = (const float*)d_in[1];
    const float* b_off = (const float*)d_in[2];
    const float* w_def = (const float*)d_in[3];
    const float* b_def = (const float*)d_in[4];
    float* out = (float*)d_out;

    char* ws = (char*)d_ws;
    float*     offs = (float*)ws;
    _Float16*  wT3  = (_Float16*)(ws + (size_t)OFFS_ELEMS * 4);
    _Float16*  woT3 = (_Float16*)(ws + (size_t)OFFS_ELEMS * 4 + (size_t)WT_ELEMS * 2);
    _Float16*  xh   = (_Float16*)(ws + XH_BYTE_OFF);

    if (ws_size >= NEED_NHWC) {
        int prep_elems = WT_ELEMS + WO3_ELEMS;
        prep_w_kernel<<<(prep_elems + 255) / 256, 256, 0, stream>>>(w_def, w_off, wT3, woT3);
        prep_x_kernel<<<BATCH * HH, 256, 0, stream>>>(x, xh);
        conv_off_nhwc<<<BATCH * HH, 512, 0, stream>>>(xh, woT3, b_off, offs);
        deform_nhwc<<<BATCH * OG * HH, 256, 0, stream>>>(xh, offs, wT3, b_def, out);
    } else {
        conv_off_fb<<<BATCH * HH, 256, 0, stream>>>(x, w_off, b_off, offs);
        deform_fb<<<BATCH * OG * HH, 256, 0, stream>>>(x, offs, w_def, b_def, out);
    }
}

// Round 9
// 168.759 us; speedup vs baseline: 5.8206x; 1.1147x over previous
//
#include <hip/hip_runtime.h>
#include <hip/hip_bf16.h>

// Problem constants (B=8, C=256, H=W=64, OG=4, Cg=64, K=9, C_off=72)
#define BATCH 8
#define CIN   256
#define HH    64
#define WW    64
#define HW    4096
#define OG    4
#define CG    64
#define COFF  72

typedef __attribute__((ext_vector_type(8))) _Float16 half8;
typedef __attribute__((ext_vector_type(4))) float floatx4;

static __device__ __forceinline__ half8 splat8(float f) {
    _Float16 h = (_Float16)f;
    return (half8){h, h, h, h, h, h, h, h};
}

// ws layout:
//   offs  fp32  [B][72][H][W]                       bytes [0, 9437184)
//   wT3   fp16  fragment-order deform weights       bytes [9437184, 9732096)
//   woT3  fp16  fragment-order offset-conv weights  bytes [9732096, 10100736)
//   xh    fp16  [b][y][x][c]  NHWC  (8*4096*256)    bytes [10100736, 26877952)
#define OFFS_ELEMS (BATCH * COFF * HH * WW)      // 2359296
#define WT_ELEMS   (OG * 9 * 4 * 2 * 64 * 8)     // 147456
#define WO3_ELEMS  (8 * 9 * 5 * 64 * 8)          // 184320
#define XH_BYTE_OFF ((size_t)OFFS_ELEMS * 4 + (size_t)WT_ELEMS * 2 + (size_t)WO3_ELEMS * 2)
#define NEED_NHWC (XH_BYTE_OFF + (size_t)BATCH * HW * CIN * 2)   // 26877952

#define PREPW_BLOCKS (((WT_ELEMS + WO3_ELEMS) + 255) / 256)      // 1296

// ---------------------------------------------------------------------------
// Merged prep: blocks [0,512) transpose x NCHW fp32 -> NHWC fp16 (one (b,y)
// row each); blocks [512, 512+1296) emit fragment-order fp16 weights.
// ---------------------------------------------------------------------------
__global__ __launch_bounds__(256) void prep_kernel(
    const float* __restrict__ x, const float* __restrict__ w_def,
    const float* __restrict__ w_off, _Float16* __restrict__ xh,
    _Float16* __restrict__ wT3, _Float16* __restrict__ woT3)
{
    const int t = threadIdx.x;
    if (blockIdx.x >= 512) {
        int i = (blockIdx.x - 512) * 256 + t;
        if (i < WT_ELEMS) {
            int j = i & 7;
            int l = (i >> 3) & 63;
            int rest = i >> 9;        // ((g*9+k)*4+mt)*2+kh
            int kh = rest & 1;
            int mt = (rest >> 1) & 3;
            int gk = rest >> 3;       // g*9+k
            int k = gk % 9, g = gk / 9;
            int o = mt * 16 + (l & 15);
            int c = kh * 32 + (l >> 4) * 8 + j;
            wT3[i] = (_Float16)w_def[((size_t)((g * CG + o) * CG + c)) * 9 + k];
        } else if (i < WT_ELEMS + WO3_ELEMS) {
            int idx = i - WT_ELEMS;
            int j = idx & 7;
            int l = (idx >> 3) & 63;
            int rest = idx >> 9;      // (chunk*9+tap)*5 + mt
            int mt = rest % 5;
            int ct = rest / 5;
            int tap = ct % 9, chunk = ct / 9;
            int o = mt * 16 + (l & 15);
            int c = chunk * 32 + (l >> 4) * 8 + j;
            float v = (o < COFF) ? w_off[((size_t)(o * CIN + c)) * 9 + tap] : 0.f;
            woT3[idx] = (_Float16)v;
        }
        return;
    }

    const int b = blockIdx.x >> 6;
    const int y = blockIdx.x & 63;

    __shared__ short tile[64][258];   // [px][c] bit-pattern of fp16

#pragma unroll
    for (int it = 0; it < 16; ++it) {
        int i  = t + it * 256;        // i < 4096
        int c  = i >> 4;
        int p4 = (i & 15) << 2;
        float4 v = *(const float4*)(x + (((size_t)(b * CIN + c)) << 12) + (y << 6) + p4);
        tile[p4 + 0][c] = __builtin_bit_cast(short, (_Float16)v.x);
        tile[p4 + 1][c] = __builtin_bit_cast(short, (_Float16)v.y);
        tile[p4 + 2][c] = __builtin_bit_cast(short, (_Float16)v.z);
        tile[p4 + 3][c] = __builtin_bit_cast(short, (_Float16)v.w);
    }
    __syncthreads();

    _Float16* dst = xh + (((size_t)(b * HW)) << 8) + ((size_t)(y * WW) << 8);
#pragma unroll
    for (int k = 0; k < 8; ++k) {
        int i  = t + k * 256;         // i < 2048
        int p  = i >> 5;
        int c8 = (i & 31) << 3;
        const unsigned* tp = (const unsigned*)&tile[p][c8];
        uint4 r = make_uint4(tp[0], tp[1], tp[2], tp[3]);
        *(uint4*)(dst + ((size_t)p << 8) + c8) = r;
    }
}

// ---------------------------------------------------------------------------
// Kernel 1 (NHWC fp16): offsets = conv3x3(x) + b_off. Implicit-GEMM MFMA f16.
// 512 threads = 8 waves: waves 0-3 M-tiles {0,1,2}, waves 4-7 {3,4}.
// A-chunk (45KB) AND B-rows (16KB) staged in LDS per chunk with register
// prefetch of the next chunk; A-frag reads are conflict-free ds_read_b128.
// ---------------------------------------------------------------------------
__global__ __launch_bounds__(512) void conv_off_nhwc(
    const _Float16* __restrict__ xh, const _Float16* __restrict__ woT3,
    const float* __restrict__ b_off, float* __restrict__ offs)
{
    const int b = blockIdx.x >> 6;
    const int h = blockIdx.x & 63;
    const int t = threadIdx.x;
    const int wv = t >> 6;
    const int l  = t & 63;
    const int lane16 = l & 15;
    const int quad   = l >> 4;
    const int pg = wv & 3;
    const int mh = wv >> 2;
    const int p  = pg * 16 + lane16;
    const int mt0 = mh ? 3 : 0;
    const int nmt = mh ? 2 : 3;

    __shared__ _Float16 xs[3][66][40];   // 15840 B, stride 80B => 2-way (free)
    __shared__ _Float16 wa[45 * 512];    // 46080 B, lane-major (conflict-free)

    floatx4 acc[3];
#pragma unroll
    for (int m = 0; m < 3; ++m) acc[m] = (floatx4){0.f, 0.f, 0.f, 0.f};

    // zero halo records (records 0 and 65 of each row) once
    if (t < 24) {
        int row = t >> 3;               // 0..2
        int rec = (t & 4) ? 65 : 0;
        int sub = t & 3;
        *(uint4*)&xs[row][rec][sub * 8] = make_uint4(0, 0, 0, 0);
    }

    uint4 ra[6], rb[2];
    auto issue = [&](int chunk) {
        const uint4* asrc = (const uint4*)(woT3 + (size_t)chunk * 45 * 512);
#pragma unroll
        for (int it = 0; it < 6; ++it) {
            int i = t + it * 512;
            ra[it] = (i < 2880) ? asrc[i] : make_uint4(0, 0, 0, 0);
        }
#pragma unroll
        for (int it = 0; it < 2; ++it) {
            int i = t + it * 512;
            int sub = i & 3, rec = (i >> 2) & 63, ky = i >> 8;
            int yy = h + ky - 1;
            uint4 v = make_uint4(0, 0, 0, 0);
            if (i < 768 && (unsigned)yy < 64u)
                v = *(const uint4*)(xh + (((size_t)(b * HW + (yy << 6) + rec)) << 8)
                                       + chunk * 32 + sub * 8);
            rb[it] = v;
        }
    };
    auto commit = [&]() {
#pragma unroll
        for (int it = 0; it < 6; ++it) {
            int i = t + it * 512;
            if (i < 2880) *(uint4*)&wa[i * 8] = ra[it];
        }
#pragma unroll
        for (int it = 0; it < 2; ++it) {
            int i = t + it * 512;
            if (i < 768) {
                int sub = i & 3, rec = (i >> 2) & 63, ky = i >> 8;
                *(uint4*)&xs[ky][rec + 1][sub * 8] = rb[it];
            }
        }
    };

    issue(0);
    commit();
    __syncthreads();

    for (int chunk = 0; chunk < 8; ++chunk) {
        if (chunk < 7) issue(chunk + 1);   // loads in flight across compute

#pragma unroll
        for (int tap = 0; tap < 9; ++tap) {
            const int ky = tap / 3, kx = tap % 3;
            half8 bfrag = *(const half8*)&xs[ky][p + kx][quad * 8];
            const _Float16* ab = wa + (size_t)(tap * 5 + mt0) * 512 + l * 8;
            for (int m = 0; m < nmt; ++m) {
                half8 afrag = *(const half8*)(ab + m * 512);
                acc[m] = __builtin_amdgcn_mfma_f32_16x16x32_f16(afrag, bfrag, acc[m], 0, 0, 0);
            }
        }

        if (chunk < 7) {
            __syncthreads();   // all reads of current LDS done
            commit();
            __syncthreads();   // new LDS visible
        }
    }

    for (int m = 0; m < nmt; ++m) {
#pragma unroll
        for (int rg = 0; rg < 4; ++rg) {
            int oc = (mt0 + m) * 16 + quad * 4 + rg;
            if (oc < COFF)
                offs[((size_t)(b * COFF + oc) << 12) + (h << 6) + p] =
                    acc[m][rg] + b_off[oc];
        }
    }
}

// ---------------------------------------------------------------------------
// Kernel 2 (NHWC fp16): deformable conv, MFMA f16, 2-ROW blocks.
// 512 threads = 8 waves: waves 0-3 -> row h0, waves 4-7 -> row h0+1; one
// shared 6-row gather window (55KB) + per-tap double-buffered A tile (16KB)
// => 71.7KB LDS, 2 blocks/CU, 16 waves/CU (2x round-8 occupancy) and half
// the window-staging traffic per output. One barrier per tap.
// ---------------------------------------------------------------------------
__global__ __launch_bounds__(512) void deform_nhwc(
    const _Float16* __restrict__ xh, const float* __restrict__ offs,
    const _Float16* __restrict__ wT3, const float* __restrict__ b_def,
    float* __restrict__ out)
{
    const int hh = blockIdx.x & 31;
    const int bg = blockIdx.x >> 5;
    const int g  = bg & 3;
    const int b  = bg >> 2;
    const int h0 = hh << 1;
    const int t  = threadIdx.x;
    const int wv = t >> 6;
    const int l  = t & 63;
    const int lane16 = l & 15;
    const int quad   = l >> 4;
    const int p  = (wv & 3) * 16 + lane16;
    const int hw = h0 + (wv >> 2);        // this wave's output row

    __shared__ _Float16 ls[6 * 64 * 72];    // gather window, 55296 B
    __shared__ _Float16 wa2[2][4096];       // per-tap A dbuf, 2 x 8192 B

    floatx4 acc[4];
#pragma unroll
    for (int mt = 0; mt < 4; ++mt) acc[mt] = (floatx4){0.f, 0.f, 0.f, 0.f};

    // ---- stage 6-row window (rows h0-2..h0+3, group g's 64 channels) ----
#pragma unroll
    for (int it = 0; it < 6; ++it) {
        int id  = it * 512 + t;          // < 3072
        int c16 = id & 7;
        int px  = (id >> 3) & 63;
        int r   = id >> 9;               // 0..5
        int r_img = h0 - 2 + r;
        uint4 v = make_uint4(0, 0, 0, 0);
        if ((unsigned)r_img < 64u)
            v = *(const uint4*)(xh + (((size_t)(b * HW + (r_img << 6) + px)) << 8)
                                   + g * 64 + c16 * 8);
        *(uint4*)&ls[(r * 64 + px) * 72 + c16 * 8] = v;
    }

    // ---- stage tap-0 A tile (8KB = 512 uint4, 1 per thread) ----
    {
        const uint4* asrc = (const uint4*)(wT3 + ((size_t)(g * 9) << 12));
        uint4 a0 = asrc[t];
        *(uint4*)&wa2[0][t * 8] = a0;
    }

    // prefetch all 18 offset values for this wave's pixel/row
    float dyv[9], dxv[9];
    {
        const float* ofb = offs + (((size_t)(b * COFF + g * 18)) * HH + hw) * WW + p;
#pragma unroll
        for (int k = 0; k < 9; ++k) {
            dyv[k] = ofb[(size_t)(2 * k) * HW];
            dxv[k] = ofb[(size_t)(2 * k + 1) * HW];
        }
    }

    __syncthreads();

    const _Float16* xg = xh + (((size_t)(b * HW)) << 8) + g * 64;

#pragma unroll
    for (int k = 0; k < 9; ++k) {
        // ---- prefetch next tap's A tile into a register ----
        uint4 pw0;
        if (k < 8) {
            const uint4* asrc = (const uint4*)(wT3 + ((size_t)(g * 9 + k + 1) << 12));
            pw0 = asrc[t];
        }

        // ---- bilinear params ----
        float py = dyv[k] + (float)(hw + (k / 3) - 1);
        float px_ = dxv[k] + (float)(p + (k % 3) - 1);
        float y0f = floorf(py), x0f = floorf(px_);
        float fy = py - y0f, fx = px_ - x0f;
        int y0 = (int)y0f, x0 = (int)x0f;
        float wy0 = ((y0 >= 0) & (y0 < HH)) ? (1.f - fy) : 0.f;
        float wy1 = ((y0 >= -1) & (y0 < HH - 1)) ? fy : 0.f;
        float wx0 = ((x0 >= 0) & (x0 < WW)) ? (1.f - fx) : 0.f;
        float wx1 = ((x0 >= -1) & (x0 < WW - 1)) ? fx : 0.f;
        int yia = min(max(y0, 0), HH - 1), yib = min(max(y0 + 1, 0), HH - 1);
        int xia = min(max(x0, 0), WW - 1), xib = min(max(x0 + 1, 0), WW - 1);
        bool inWin = (y0 >= h0 - 2) & (y0 <= h0 + 2);

        const int co = quad * 8;
        int wa_ = min(max(yia - (h0 - 2), 0), 5);
        int wb_ = min(max(yib - (h0 - 2), 0), 5);
        const _Float16* pa = ls + ((wa_ * 64 + xia) * 72);
        const _Float16* pb = ls + ((wa_ * 64 + xib) * 72);
        const _Float16* pc = ls + ((wb_ * 64 + xia) * 72);
        const _Float16* pd = ls + ((wb_ * 64 + xib) * 72);

        half8 aL = *(const half8*)(pa + co);
        half8 bL = *(const half8*)(pb + co);
        half8 cL = *(const half8*)(pc + co);
        half8 dL = *(const half8*)(pd + co);
        half8 aH = *(const half8*)(pa + co + 32);
        half8 bH = *(const half8*)(pb + co + 32);
        half8 cH = *(const half8*)(pc + co + 32);
        half8 dH = *(const half8*)(pd + co + 32);

        if (!inWin) {   // rare: sample escaped the staged window (still exact)
            const _Float16* qa = xg + (((size_t)((yia << 6) + xia)) << 8);
            const _Float16* qb = xg + (((size_t)((yia << 6) + xib)) << 8);
            const _Float16* qc = xg + (((size_t)((yib << 6) + xia)) << 8);
            const _Float16* qd = xg + (((size_t)((yib << 6) + xib)) << 8);
            aL = *(const half8*)(qa + co);  aH = *(const half8*)(qa + co + 32);
            bL = *(const half8*)(qb + co);  bH = *(const half8*)(qb + co + 32);
            cL = *(const half8*)(qc + co);  cH = *(const half8*)(qc + co + 32);
            dL = *(const half8*)(qd + co);  dH = *(const half8*)(qd + co + 32);
        }

        // ---- packed fp16 blend ----
        half8 W00 = splat8(wy0 * wx0), W01 = splat8(wy0 * wx1);
        half8 W10 = splat8(wy1 * wx0), W11 = splat8(wy1 * wx1);
        half8 f0 = aL * W00 + bL * W01 + cL * W10 + dL * W11;
        half8 f1 = aH * W00 + bH * W01 + cH * W10 + dH * W11;

        // ---- A-frags from LDS dbuf + MFMA ----
        const _Float16* wk = &wa2[k & 1][l * 8];
#pragma unroll
        for (int mt = 0; mt < 4; ++mt) {
            half8 a0 = *(const half8*)(wk + (mt * 2 + 0) * 512);
            half8 a1 = *(const half8*)(wk + (mt * 2 + 1) * 512);
            acc[mt] = __builtin_amdgcn_mfma_f32_16x16x32_f16(a0, f0, acc[mt], 0, 0, 0);
            acc[mt] = __builtin_amdgcn_mfma_f32_16x16x32_f16(a1, f1, acc[mt], 0, 0, 0);
        }

        // ---- commit next tap's A tile; single barrier per tap ----
        if (k < 8) {
            *(uint4*)&wa2[(k + 1) & 1][t * 8] = pw0;
            __syncthreads();
        }
    }

#pragma unroll
    for (int mt = 0; mt < 4; ++mt) {
#pragma unroll
        for (int rg = 0; rg < 4; ++rg) {
            int o = mt * 16 + quad * 4 + rg;
            float v = acc[mt][rg] + b_def[g * CG + o];
            out[((size_t)(b * CIN + g * CG + o) * HH + hw) * WW + p] = v;
        }
    }
}

// ===========================================================================
// FALLBACK PATH (ws too small for xh): fp32 correctness-first (not expected
// to be taken -- ws has been >= 26.9MB in all rounds).
// ===========================================================================
__global__ __launch_bounds__(256) void conv_off_fb(
    const float* __restrict__ x, const float* __restrict__ w_off,
    const float* __restrict__ b_off, float* __restrict__ offs)
{
    const int b = blockIdx.x >> 6;
    const int h = blockIdx.x & 63;
    const int t = threadIdx.x;
    const int w = t & 63;
    const int q = t >> 6;

    __shared__ float xsf[3][8][WW + 2];
    __shared__ float wtf[9][8][COFF];

    float acc[18];
#pragma unroll
    for (int j = 0; j < 18; ++j) acc[j] = 0.f;

    for (int c0 = 0; c0 < CIN; c0 += 8) {
        __syncthreads();
        for (int i = t; i < 3 * 8 * (WW + 2); i += 256) {
            int wp = i % (WW + 2);
            int rem = i / (WW + 2);
            int cc = rem % 8;
            int ky = rem / 8;
            int yy = h + ky - 1;
            int xx = wp - 1;
            float v = 0.f;
            if (yy >= 0 && yy < HH && xx >= 0 && xx < WW)
                v = x[(((size_t)b * CIN + c0 + cc) * HH + yy) * WW + xx];
            xsf[ky][cc][wp] = v;
        }
        for (int i = t; i < 9 * 8 * COFF; i += 256) {
            int oc = i % COFF;
            int rem = i / COFF;
            int cc = rem % 8;
            int tap = rem / 8;
            wtf[tap][cc][oc] = w_off[((size_t)oc * CIN + c0 + cc) * 9 + tap];
        }
        __syncthreads();
        for (int tap = 0; tap < 9; ++tap) {
            const int ky = tap / 3, kx = tap % 3;
#pragma unroll
            for (int cc = 0; cc < 8; ++cc) {
                float xv = xsf[ky][cc][w + kx];
#pragma unroll
                for (int j = 0; j < 18; ++j)
                    acc[j] += xv * wtf[tap][cc][q * 18 + j];
            }
        }
    }
#pragma unroll
    for (int j = 0; j < 18; ++j) {
        int oc = q * 18 + j;
        offs[(((size_t)b * COFF + oc) * HH + h) * WW + w] = acc[j] + b_off[oc];
    }
}

__global__ __launch_bounds__(256) void deform_fb(
    const float* __restrict__ x, const float* __restrict__ offs,
    const float* __restrict__ w_def, const float* __restrict__ b_def,
    float* __restrict__ out)
{
    const int h  = blockIdx.x & 63;
    const int bg = blockIdx.x >> 6;
    const int g  = bg & 3;
    const int b  = bg >> 2;
    const int t  = threadIdx.x;
    const int w  = t & 63;
    const int q  = t >> 6;

    __shared__ float vlds[CG][WW];
    __shared__ float wt2[CG][CG];
    __shared__ int   sidx[4][WW];
    __shared__ float swgt[4][WW];

    float acc[16];
#pragma unroll
    for (int j = 0; j < 16; ++j) acc[j] = 0.f;

    const float* xg = x + ((size_t)(b * CIN + g * CG)) * HW;

    for (int k = 0; k < 9; ++k) {
        __syncthreads();
        if (t < 64) {
            const int ky = k / 3 - 1, kx = k % 3 - 1;
            size_t obase = (((size_t)b * COFF + g * 18 + k * 2) * HH + h) * WW + w;
            float dy = offs[obase];
            float dx = offs[obase + (size_t)HW];
            float py = dy + (float)(h + ky);
            float px = dx + (float)(w + kx);
            float y0 = floorf(py), x0 = floorf(px);
            float fy = py - y0, fx = px - x0;
#pragma unroll
            for (int cn = 0; cn < 4; ++cn) {
                float yy = y0 + (float)(cn >> 1);
                float xx = x0 + (float)(cn & 1);
                float wy = (cn >> 1) ? fy : (1.f - fy);
                float wx = (cn & 1) ? fx : (1.f - fx);
                bool valid = (yy >= 0.f) && (yy < (float)HH) &&
                             (xx >= 0.f) && (xx < (float)WW);
                int yi = (int)fminf(fmaxf(yy, 0.f), (float)(HH - 1));
                int xi = (int)fminf(fmaxf(xx, 0.f), (float)(WW - 1));
                sidx[cn][w] = yi * WW + xi;
                swgt[cn][w] = valid ? (wy * wx) : 0.f;
            }
        }
        for (int i = t; i < CG * CG; i += 256) {
            int o = i >> 6, c = i & 63;
            wt2[c][o] = w_def[((size_t)(g * CG + o) * CG + c) * 9 + k];
        }
        __syncthreads();

        int   i0 = sidx[0][w], i1 = sidx[1][w], i2 = sidx[2][w], i3 = sidx[3][w];
        float g0 = swgt[0][w], g1 = swgt[1][w], g2 = swgt[2][w], g3 = swgt[3][w];
#pragma unroll
        for (int j = 0; j < 16; ++j) {
            int c = q * 16 + j;
            const float* xc = xg + (size_t)c * HW;
            float v = g0 * xc[i0] + g1 * xc[i1] + g2 * xc[i2] + g3 * xc[i3];
            vlds[c][w] = v;
        }
        __syncthreads();

#pragma unroll 4
        for (int c = 0; c < CG; ++c) {
            float xv = vlds[c][w];
#pragma unroll
            for (int j = 0; j < 16; ++j)
                acc[j] += xv * wt2[c][q * 16 + j];
        }
    }

#pragma unroll
    for (int j = 0; j < 16; ++j) {
        int o = q * 16 + j;
        out[(((size_t)b * CIN + g * CG + o) * HH + h) * WW + w] =
            acc[j] + b_def[g * CG + o];
    }
}

extern "C" void kernel_launch(void* const* d_in, const int* in_sizes, int n_in,
                              void* d_out, int out_size, void* d_ws, size_t ws_size,
                              hipStream_t stream) {
    const float* x     = (const float*)d_in[0];
    const float* w_off = (const float*)d_in[1];
    const float* b_off = (const float*)d_in[2];
    const float* w_def = (const float*)d_in[3];
    const float* b_def = (const float*)d_in[4];
    float* out = (float*)d_out;

    char* ws = (char*)d_ws;
    float*     offs = (float*)ws;
    _Float16*  wT3  = (_Float16*)(ws + (size_t)OFFS_ELEMS * 4);
    _Float16*  woT3 = (_Float16*)(ws + (size_t)OFFS_ELEMS * 4 + (size_t)WT_ELEMS * 2);
    _Float16*  xh   = (_Float16*)(ws + XH_BYTE_OFF);

    if (ws_size >= NEED_NHWC) {
        prep_kernel<<<512 + PREPW_BLOCKS, 256, 0, stream>>>(x, w_def, w_off, xh, wT3, woT3);
        conv_off_nhwc<<<BATCH * HH, 512, 0, stream>>>(xh, woT3, b_off, offs);
        deform_nhwc<<<BATCH * OG * 32, 512, 0, stream>>>(xh, offs, wT3, b_def, out);
    } else {
        conv_off_fb<<<BATCH * HH, 256, 0, stream>>>(x, w_off, b_off, offs);
        deform_fb<<<BATCH * OG * HH, 256, 0, stream>>>(x, offs, w_def, b_def, out);
    }
}